// Round 15
// baseline (351.106 us; speedup 1.0000x reference)
//
#include <hip/hip_runtime.h>
#include <cstdint>
#include <cstddef>

#define DF 128      // feature dim
#define HATT 64     // attention hidden dim
#define SL 64       // edge slices for graph prep
#define RPB 1280    // max rows per range-block (LDS counters)

static inline int divup(int a, int b) { return (a + b - 1) / b; }

typedef int vint4 __attribute__((ext_vector_type(4)));              // nontemporal-compatible
typedef unsigned short vus8 __attribute__((ext_vector_type(8)));    // bf16x8 gather (16B)

struct U16x4 { unsigned short x, y, z, w; };

// bf16 round-to-nearest-even (LINEAR aggregation only; weight->deg->rsqrt chain stays fp32)
static __device__ __forceinline__ unsigned short f2bf(float f) {
    unsigned int u = __float_as_uint(f);
    u = (u + 0x7FFFu + ((u >> 16) & 1u)) >> 16;
    return (unsigned short)u;
}
static __device__ __forceinline__ float bf2f(unsigned short b) {
    return __uint_as_float(((unsigned int)b) << 16);
}

// ---------------- graph prep ----------------
__global__ __launch_bounds__(256) void hist2_kernel(const int* __restrict__ row,
                                                    int* __restrict__ cnt2,
                                                    int E, int n, int ranges, int rpb, int es) {
    int rb = blockIdx.x % ranges;
    int s  = blockIdx.x / ranges;
    int lo = rb * rpb, hi = min(lo + rpb, n);
    int rows = hi - lo;
    __shared__ int lc[RPB];
    for (int j = threadIdx.x; j < rows; j += 256) lc[j] = 0;
    __syncthreads();
    int i0 = s * es, i1 = min(i0 + es, E);
    const vint4* rv = (const vint4*)row;
    for (int j = i0 / 4 + threadIdx.x; j < i1 / 4; j += 256) {
        vint4 r4 = __builtin_nontemporal_load(rv + j);
        if (r4.x >= lo && r4.x < hi) atomicAdd(&lc[r4.x - lo], 1);
        if (r4.y >= lo && r4.y < hi) atomicAdd(&lc[r4.y - lo], 1);
        if (r4.z >= lo && r4.z < hi) atomicAdd(&lc[r4.z - lo], 1);
        if (r4.w >= lo && r4.w < hi) atomicAdd(&lc[r4.w - lo], 1);
    }
    __syncthreads();
    for (int j = threadIdx.x; j < rows; j += 256) cnt2[(size_t)s * n + lo + j] = lc[j];
}

__global__ __launch_bounds__(256) void scanRT_kernel(int* __restrict__ cnt2,
                                                     int* __restrict__ tot, int n) {
    __shared__ int tile[SL][65];
    int r0 = blockIdx.x * 64;
    int w = threadIdx.x >> 6;
    int lane = threadIdx.x & 63;
    int rows = min(64, n - r0);
    for (int s = w; s < SL; s += 4) {
        int v = (lane < rows) ? cnt2[(size_t)s * n + r0 + lane] : 0;
        tile[s][lane] = v;
    }
    __syncthreads();
    int t = threadIdx.x;
    if (t < rows) {
        int run = 0;
#pragma unroll
        for (int s = 0; s < SL; ++s) {
            int v = tile[s][t];
            tile[s][t] = run;
            run += v;
        }
        tot[r0 + t] = run;
    }
    __syncthreads();
    for (int s = w; s < SL; s += 4) {
        if (lane < rows) cnt2[(size_t)s * n + r0 + lane] = tile[s][lane];
    }
}

__global__ __launch_bounds__(1024) void scanT_kernel(const int* __restrict__ tot,
                                                     int* __restrict__ row_ptr, int n) {
    __shared__ int sums[1024];
    int t = threadIdx.x;
    int chunk = (n + 1023) >> 10;
    int start = t * chunk, end = min(start + chunk, n);
    int s = 0;
    for (int r = start; r < end; ++r) s += tot[r];
    sums[t] = s;
    __syncthreads();
    for (int off = 1; off < 1024; off <<= 1) {
        int v = (t >= off) ? sums[t - off] : 0;
        __syncthreads();
        sums[t] += v;
        __syncthreads();
    }
    int run = sums[t] - s;
    for (int r = start; r < end; ++r) {
        row_ptr[r] = run;
        run += tot[r];
    }
    if (t == 1023) row_ptr[n] = sums[1023];
}

__global__ __launch_bounds__(256) void scatter2_kernel(const int* __restrict__ row,
                                                       const int* __restrict__ col,
                                                       const int* __restrict__ cnt2,
                                                       const int* __restrict__ row_ptr,
                                                       unsigned short* __restrict__ col_s,
                                                       int E, int n, int ranges, int rpb, int es) {
    int rb = blockIdx.x % ranges;
    int s  = blockIdx.x / ranges;
    int lo = rb * rpb, hi = min(lo + rpb, n);
    int rows = hi - lo;
    __shared__ int cur[RPB];
    for (int j = threadIdx.x; j < rows; j += 256)
        cur[j] = cnt2[(size_t)s * n + lo + j] + row_ptr[lo + j];
    __syncthreads();
    int i0 = s * es, i1 = min(i0 + es, E);
    const vint4* rv = (const vint4*)row;
    const vint4* cv = (const vint4*)col;
    for (int j = i0 / 4 + threadIdx.x; j < i1 / 4; j += 256) {
        vint4 r4 = __builtin_nontemporal_load(rv + j);
        bool b0 = (r4.x >= lo && r4.x < hi);
        bool b1 = (r4.y >= lo && r4.y < hi);
        bool b2 = (r4.z >= lo && r4.z < hi);
        bool b3 = (r4.w >= lo && r4.w < hi);
        if (b0 | b1 | b2 | b3) {
            vint4 c4 = __builtin_nontemporal_load(cv + j);
            if (b0) { int p = atomicAdd(&cur[r4.x - lo], 1); col_s[p] = (unsigned short)c4.x; }
            if (b1) { int p = atomicAdd(&cur[r4.y - lo], 1); col_s[p] = (unsigned short)c4.y; }
            if (b2) { int p = atomicAdd(&cur[r4.z - lo], 1); col_s[p] = (unsigned short)c4.z; }
            if (b3) { int p = atomicAdd(&cur[r4.w - lo], 1); col_s[p] = (unsigned short)c4.w; }
        }
    }
}

// ---------------- split x + squared norms ----------------
__global__ __launch_bounds__(256) void split_x_kernel(const float* __restrict__ x,
                                                      float* __restrict__ xA,
                                                      float* __restrict__ xB,
                                                      float* __restrict__ sqn, int n) {
    int wid = (blockIdx.x * blockDim.x + threadIdx.x) >> 6;
    int lane = threadIdx.x & 63;
    if (wid >= n) return;
    float v0 = x[(size_t)wid * DF + lane];
    float v1 = x[(size_t)wid * DF + 64 + lane];
    xA[(size_t)wid * 64 + lane] = v0;
    xB[(size_t)wid * 64 + lane] = v1;
    float s = v0 * v0 + v1 * v1;
    for (int off = 32; off; off >>= 1) s += __shfl_xor(s, off);
    if (lane == 0) sqn[wid] = s;
}

// ---------------- edge weights (fp32 tables, branchless keep) ----------------
__global__ __launch_bounds__(256) void edgewA_kernel(const float* __restrict__ tA,
                                                     const unsigned short* __restrict__ col_s,
                                                     const int* __restrict__ row_ptr,
                                                     float* __restrict__ dpart, int n) {
    int wid = (blockIdx.x * blockDim.x + threadIdx.x) >> 6;
    int lane = threadIdx.x & 63;
    if (wid >= n) return;
    int sub = lane & 15, g = lane >> 4;
    int s = row_ptr[wid], e = row_ptr[wid + 1];
    float4 a = ((const float4*)(tA + (size_t)wid * 64))[sub];
    for (int base = s; base < e; base += 64) {
        int m = e - base; if (m > 64) m = 64;
        int cc = 0;
        if (lane < m) cc = (int)col_s[base + lane];
        float dkeep = 0.f;
#define EWA_BODY(CHK)                                                        \
        _Pragma("unroll")                                                    \
        for (int it = 0; it < 16; ++it) {                                    \
            int idx = g * 16 + it;                                           \
            int c = __shfl(cc, idx);                                         \
            if (CHK) {                                                       \
                float4 b = ((const float4*)(tA + (size_t)c * 64))[sub];      \
                float d = a.x * b.x + a.y * b.y + a.z * b.z + a.w * b.w;     \
                d += __shfl_xor(d, 8); d += __shfl_xor(d, 4);                \
                d += __shfl_xor(d, 2); d += __shfl_xor(d, 1);                \
                dkeep = (sub == it) ? d : dkeep;                             \
            }                                                                \
        }
        if (m == 64) { EWA_BODY(true) } else { EWA_BODY(idx < m) }
#undef EWA_BODY
        if (lane < m) dpart[base + lane] = dkeep;
    }
}

__global__ __launch_bounds__(256) void edgewB1_kernel(const float* __restrict__ tB,
                                                      const float* __restrict__ sqn,
                                                      const unsigned short* __restrict__ col_s,
                                                      const int* __restrict__ row_ptr,
                                                      const float* __restrict__ dpart,
                                                      float* __restrict__ wA,
                                                      float* __restrict__ wB,
                                                      float* __restrict__ disA,
                                                      float* __restrict__ disB, int n) {
    int wid = (blockIdx.x * blockDim.x + threadIdx.x) >> 6;
    int lane = threadIdx.x & 63;
    if (wid >= n) return;
    int sub = lane & 15, g = lane >> 4;
    int s = row_ptr[wid], e = row_ptr[wid + 1];
    float4 a = ((const float4*)(tB + (size_t)wid * 64))[sub];
    float na = sqn[wid];
    float accA = 0.f, accB = 0.f;
    for (int base = s; base < e; base += 64) {
        int m = e - base; if (m > 64) m = 64;
        int cc = 0; float dp = 0.f;
        if (lane < m) {
            cc = (int)col_s[base + lane];
            dp = dpart[base + lane];
        }
        float dkeep = 0.f;
#define EWB1_BODY(CHK)                                                       \
        _Pragma("unroll")                                                    \
        for (int it = 0; it < 16; ++it) {                                    \
            int idx = g * 16 + it;                                           \
            int c = __shfl(cc, idx);                                         \
            if (CHK) {                                                       \
                float4 b = ((const float4*)(tB + (size_t)c * 64))[sub];      \
                float d = a.x * b.x + a.y * b.y + a.z * b.z + a.w * b.w;     \
                d += __shfl_xor(d, 8); d += __shfl_xor(d, 4);                \
                d += __shfl_xor(d, 2); d += __shfl_xor(d, 1);                \
                dkeep = (sub == it) ? d : dkeep;                             \
            }                                                                \
        }
        if (m == 64) { EWB1_BODY(true) } else { EWB1_BODY(idx < m) }
#undef EWB1_BODY
        if (lane < m) {
            float d = dkeep + dp;
            float nb = sqn[cc];
            float cw = d / fmaxf(sqrtf(na * nb), 1e-8f);
            float ew = sqrtf(fmaxf(na + nb - 2.f * d, 0.f) + 1e-12f);
            wA[base + lane] = cw;
            wB[base + lane] = ew;
            accA += cw;
            accB += ew;
        }
    }
#pragma unroll
    for (int off = 32; off; off >>= 1) {
        accA += __shfl_xor(accA, off);
        accB += __shfl_xor(accB, off);
    }
    if (lane == 0) {
        float dA = 1.f + accA;
        disA[wid] = (dA > 0.f) ? rsqrtf(fmaxf(dA, 1e-12f)) : 0.f;
        float dB = 1.f + accB;
        disB[wid] = (dB > 0.f) ? rsqrtf(fmaxf(dB, 1e-12f)) : 0.f;
    }
}

__global__ __launch_bounds__(256) void edgewA2_kernel(const float* __restrict__ t0,
                                                      const float* __restrict__ t1,
                                                      const unsigned short* __restrict__ col_s,
                                                      const int* __restrict__ row_ptr,
                                                      float* __restrict__ dp0,
                                                      float* __restrict__ dp1, int n) {
    int br = blockIdx.x & 1;
    int wid = (blockIdx.x >> 1) * 4 + (threadIdx.x >> 6);
    int lane = threadIdx.x & 63;
    if (wid >= n) return;
    const float* tA = br ? t1 : t0;
    float* dpart = br ? dp1 : dp0;
    int sub = lane & 15, g = lane >> 4;
    int s = row_ptr[wid], e = row_ptr[wid + 1];
    float4 a = ((const float4*)(tA + (size_t)wid * 64))[sub];
    for (int base = s; base < e; base += 64) {
        int m = e - base; if (m > 64) m = 64;
        int cc = 0;
        if (lane < m) cc = (int)col_s[base + lane];
        float dkeep = 0.f;
#define EWA2_BODY(CHK)                                                       \
        _Pragma("unroll")                                                    \
        for (int it = 0; it < 16; ++it) {                                    \
            int idx = g * 16 + it;                                           \
            int c = __shfl(cc, idx);                                         \
            if (CHK) {                                                       \
                float4 b = ((const float4*)(tA + (size_t)c * 64))[sub];      \
                float d = a.x * b.x + a.y * b.y + a.z * b.z + a.w * b.w;     \
                d += __shfl_xor(d, 8); d += __shfl_xor(d, 4);                \
                d += __shfl_xor(d, 2); d += __shfl_xor(d, 1);                \
                dkeep = (sub == it) ? d : dkeep;                             \
            }                                                                \
        }
        if (m == 64) { EWA2_BODY(true) } else { EWA2_BODY(idx < m) }
#undef EWA2_BODY
        if (lane < m) dpart[base + lane] = dkeep;
    }
}

__global__ __launch_bounds__(256) void edgewB2_kernel(const float* __restrict__ t0B,
                                                      const float* __restrict__ t1B,
                                                      const float* __restrict__ sqn1,
                                                      const float* __restrict__ sqn2,
                                                      const unsigned short* __restrict__ col_s,
                                                      const int* __restrict__ row_ptr,
                                                      const float* __restrict__ dp0,
                                                      const float* __restrict__ dp1,
                                                      float* __restrict__ wsA,
                                                      float* __restrict__ wsB,
                                                      float* __restrict__ disA,
                                                      float* __restrict__ disB, int n) {
    int br = blockIdx.x & 1;
    int wid = (blockIdx.x >> 1) * 4 + (threadIdx.x >> 6);
    int lane = threadIdx.x & 63;
    if (wid >= n) return;
    const float* tB = br ? t1B : t0B;
    const float* sq = br ? sqn2 : sqn1;
    const float* dpart = br ? dp1 : dp0;
    float* wOut = br ? wsB : wsA;
    float* disOut = br ? disB : disA;
    int sub = lane & 15, g = lane >> 4;
    int s = row_ptr[wid], e = row_ptr[wid + 1];
    float4 a = ((const float4*)(tB + (size_t)wid * 64))[sub];
    float na = sq[wid];
    float acc = 0.f;
    for (int base = s; base < e; base += 64) {
        int m = e - base; if (m > 64) m = 64;
        int cc = 0; float dp = 0.f;
        if (lane < m) {
            cc = (int)col_s[base + lane];
            dp = dpart[base + lane];
        }
        float dkeep = 0.f;
#define EWB2_BODY(CHK)                                                       \
        _Pragma("unroll")                                                    \
        for (int it = 0; it < 16; ++it) {                                    \
            int idx = g * 16 + it;                                           \
            int c = __shfl(cc, idx);                                         \
            if (CHK) {                                                       \
                float4 b = ((const float4*)(tB + (size_t)c * 64))[sub];      \
                float d = a.x * b.x + a.y * b.y + a.z * b.z + a.w * b.w;     \
                d += __shfl_xor(d, 8); d += __shfl_xor(d, 4);                \
                d += __shfl_xor(d, 2); d += __shfl_xor(d, 1);                \
                dkeep = (sub == it) ? d : dkeep;                             \
            }                                                                \
        }
        if (m == 64) { EWB2_BODY(true) } else { EWB2_BODY(idx < m) }
#undef EWB2_BODY
        if (lane < m) {
            float d = dkeep + dp;
            float nb = sq[cc];
            float w;
            if (br == 0) w = d / fmaxf(sqrtf(na * nb), 1e-8f);
            else w = sqrtf(fmaxf(na + nb - 2.f * d, 0.f) + 1e-12f);
            wOut[base + lane] = w;
            acc += w;
        }
    }
#pragma unroll
    for (int off = 32; off; off >>= 1) acc += __shfl_xor(acc, off);
    if (lane == 0) {
        float dg = 1.f + acc;
        disOut[wid] = (dg > 0.f) ? rsqrtf(fmaxf(dg, 1e-12f)) : 0.f;
    }
}

// ---------------- pre-scale edge weights by dis[col] (in place) ----------------
__global__ __launch_bounds__(256) void scale_wd_kernel(float* __restrict__ wsA,
                                                       float* __restrict__ wsB,
                                                       const unsigned short* __restrict__ col_s,
                                                       const float* __restrict__ disA,
                                                       const float* __restrict__ disB, int E4) {
    int j = blockIdx.x * 256 + threadIdx.x;
    if (j >= E4) return;
    U16x4 c4 = ((const U16x4*)col_s)[j];
    float4 wa = ((const float4*)wsA)[j];
    float4 wb = ((const float4*)wsB)[j];
    wa.x *= disA[c4.x]; wa.y *= disA[c4.y]; wa.z *= disA[c4.z]; wa.w *= disA[c4.w];
    wb.x *= disB[c4.x]; wb.y *= disB[c4.y]; wb.z *= disB[c4.z]; wb.w *= disB[c4.w];
    ((float4*)wsA)[j] = wa;
    ((float4*)wsB)[j] = wb;
}

// ---------------- dense matmuls -> interleaved bf16 h [n][128] ----------------
__global__ __launch_bounds__(256) void mm_kernel(const float* __restrict__ inA,
                                                 const float* __restrict__ inB,
                                                 int strideIn,
                                                 const float* __restrict__ W,
                                                 unsigned short* __restrict__ hab, int n) {
    int wid = (blockIdx.x * blockDim.x + threadIdx.x) >> 6;
    int lane = threadIdx.x & 63;
    int i0 = wid * 4;
    if (i0 >= n) return;
    float v0[4], v1[4];
#pragma unroll
    for (int r = 0; r < 4; ++r) {
        int i = i0 + r;
        if (i < n) { v0[r] = inA[(size_t)i * strideIn + lane]; v1[r] = inB[(size_t)i * strideIn + lane]; }
        else { v0[r] = 0.f; v1[r] = 0.f; }
    }
    float acc0[4] = {0.f, 0.f, 0.f, 0.f};
    float acc1[4] = {0.f, 0.f, 0.f, 0.f};
#pragma unroll 4
    for (int k = 0; k < 64; ++k) {
        float w0 = W[k * DF + lane];
        float w1 = W[k * DF + 64 + lane];
#pragma unroll
        for (int r = 0; r < 4; ++r) {
            float a = __shfl(v0[r], k);
            acc0[r] = fmaf(a, w0, acc0[r]);
            acc1[r] = fmaf(a, w1, acc1[r]);
        }
    }
#pragma unroll 4
    for (int k = 0; k < 64; ++k) {
        float w0 = W[(k + 64) * DF + lane];
        float w1 = W[(k + 64) * DF + 64 + lane];
#pragma unroll
        for (int r = 0; r < 4; ++r) {
            float a = __shfl(v1[r], k);
            acc0[r] = fmaf(a, w0, acc0[r]);
            acc1[r] = fmaf(a, w1, acc1[r]);
        }
    }
#pragma unroll
    for (int r = 0; r < 4; ++r) {
        int i = i0 + r;
        if (i < n) {
            hab[(size_t)i * DF + lane] = f2bf(acc0[r]);
            hab[(size_t)i * DF + 64 + lane] = f2bf(acc1[r]);
        }
    }
}

// paired layer-2 mm: branch parity -> interleaved bf16 h
__global__ __launch_bounds__(256) void mm2_kernel(const float* __restrict__ x1A_,
                                                  const float* __restrict__ x1B_,
                                                  const float* __restrict__ x2A_,
                                                  const float* __restrict__ x2B_,
                                                  const float* __restrict__ W,
                                                  unsigned short* __restrict__ h1ab,
                                                  unsigned short* __restrict__ h2ab, int n) {
    int br = blockIdx.x & 1;
    const float* inA = br ? x2A_ : x1A_;
    const float* inB = br ? x2B_ : x1B_;
    unsigned short* hab = br ? h2ab : h1ab;
    int wid = (blockIdx.x >> 1) * 4 + (threadIdx.x >> 6);
    int lane = threadIdx.x & 63;
    int i0 = wid * 4;
    if (i0 >= n) return;
    float v0[4], v1[4];
#pragma unroll
    for (int r = 0; r < 4; ++r) {
        int i = i0 + r;
        if (i < n) { v0[r] = inA[(size_t)i * 64 + lane]; v1[r] = inB[(size_t)i * 64 + lane]; }
        else { v0[r] = 0.f; v1[r] = 0.f; }
    }
    float acc0[4] = {0.f, 0.f, 0.f, 0.f};
    float acc1[4] = {0.f, 0.f, 0.f, 0.f};
#pragma unroll 4
    for (int k = 0; k < 64; ++k) {
        float w0 = W[k * DF + lane];
        float w1 = W[k * DF + 64 + lane];
#pragma unroll
        for (int r = 0; r < 4; ++r) {
            float a = __shfl(v0[r], k);
            acc0[r] = fmaf(a, w0, acc0[r]);
            acc1[r] = fmaf(a, w1, acc1[r]);
        }
    }
#pragma unroll 4
    for (int k = 0; k < 64; ++k) {
        float w0 = W[(k + 64) * DF + lane];
        float w1 = W[(k + 64) * DF + 64 + lane];
#pragma unroll
        for (int r = 0; r < 4; ++r) {
            float a = __shfl(v1[r], k);
            acc0[r] = fmaf(a, w0, acc0[r]);
            acc1[r] = fmaf(a, w1, acc1[r]);
        }
    }
#pragma unroll
    for (int r = 0; r < 4; ++r) {
        int i = i0 + r;
        if (i < n) {
            hab[(size_t)i * DF + lane] = f2bf(acc0[r]);
            hab[(size_t)i * DF + 64 + lane] = f2bf(acc1[r]);
        }
    }
}

// ---------------- unified SpMM: wave per (node, branch), full-row vus8 gathers ----------------
// Pre-scaled weights wd = w*dis[col] (no random dis gather in critical chain).
// RELU=1: relu + per-branch squared-norm output (layer 1). RELU=0: plain (layer 2).
template <int RELU>
__global__ __launch_bounds__(256) void spmm_kernel(const unsigned short* __restrict__ hab0,
                                                   const unsigned short* __restrict__ hab1,
                                                   const float* __restrict__ wd0,
                                                   const float* __restrict__ wd1,
                                                   const unsigned short* __restrict__ col_s,
                                                   const float* __restrict__ dis0,
                                                   const float* __restrict__ dis1,
                                                   const int* __restrict__ row_ptr,
                                                   const float* __restrict__ bias,
                                                   float* __restrict__ o0A, float* __restrict__ o0B,
                                                   float* __restrict__ o1A, float* __restrict__ o1B,
                                                   float* __restrict__ sq0, float* __restrict__ sq1,
                                                   int n) {
    int br = blockIdx.x & 1;
    const unsigned short* hab = br ? hab1 : hab0;
    const float* wd = br ? wd1 : wd0;
    const float* disp = br ? dis1 : dis0;
    float* outA = br ? o1A : o0A;
    float* outB = br ? o1B : o0B;
    int wid = (blockIdx.x >> 1) * 4 + (threadIdx.x >> 6);
    int lane = threadIdx.x & 63;
    if (wid >= n) return;
    int sub = lane & 15, g = lane >> 4;
    int s = row_ptr[wid], e = row_ptr[wid + 1];
    float di = disp[wid];
    float acc[8];
#pragma unroll
    for (int j = 0; j < 8; ++j) acc[j] = 0.f;
    for (int base = s; base < e; base += 64) {
        int m = e - base; if (m > 64) m = 64;
        int cc = 0; float wv = 0.f;
        if (lane < m) {
            cc = (int)col_s[base + lane];
            wv = wd[base + lane];
        }
#define SPM_BODY(CHK)                                                        \
        _Pragma("unroll")                                                    \
        for (int it = 0; it < 16; ++it) {                                    \
            int idx = it * 4 + g;                                            \
            int c = __shfl(cc, idx);                                         \
            float ce = __shfl(wv, idx);                                      \
            if (CHK) {                                                       \
                vus8 gv = ((const vus8*)(hab + (size_t)c * DF))[sub];        \
                _Pragma("unroll")                                            \
                for (int j = 0; j < 8; ++j)                                  \
                    acc[j] = fmaf(ce, bf2f(gv[j]), acc[j]);                  \
            }                                                                \
        }
        if (m == 64) { SPM_BODY(true) } else { SPM_BODY(idx < m) }
#undef SPM_BODY
    }
#pragma unroll
    for (int off = 16; off <= 32; off <<= 1) {
#pragma unroll
        for (int j = 0; j < 8; ++j) acc[j] += __shfl_xor(acc[j], off);
    }
    // epilogue: self term + bias (+relu); lane sub holds features sub*8 .. sub*8+7
    vus8 hv = ((const vus8*)(hab + (size_t)wid * DF))[sub];
    float4 bbl = ((const float4*)bias)[sub * 2];
    float4 bbh = ((const float4*)bias)[sub * 2 + 1];
    float o[8];
    o[0] = di * (acc[0] + di * bf2f(hv[0])) + bbl.x;
    o[1] = di * (acc[1] + di * bf2f(hv[1])) + bbl.y;
    o[2] = di * (acc[2] + di * bf2f(hv[2])) + bbl.z;
    o[3] = di * (acc[3] + di * bf2f(hv[3])) + bbl.w;
    o[4] = di * (acc[4] + di * bf2f(hv[4])) + bbh.x;
    o[5] = di * (acc[5] + di * bf2f(hv[5])) + bbh.y;
    o[6] = di * (acc[6] + di * bf2f(hv[6])) + bbh.z;
    o[7] = di * (acc[7] + di * bf2f(hv[7])) + bbh.w;
    if (RELU) {
#pragma unroll
        for (int j = 0; j < 8; ++j) o[j] = fmaxf(o[j], 0.f);
    }
    if (g == 0) {
        float4 lo = make_float4(o[0], o[1], o[2], o[3]);
        float4 hi = make_float4(o[4], o[5], o[6], o[7]);
        if (sub < 8) {
            ((float4*)(outA + (size_t)wid * 64))[sub * 2] = lo;
            ((float4*)(outA + (size_t)wid * 64))[sub * 2 + 1] = hi;
        } else {
            int sb = sub - 8;
            ((float4*)(outB + (size_t)wid * 64))[sb * 2] = lo;
            ((float4*)(outB + (size_t)wid * 64))[sb * 2 + 1] = hi;
        }
    }
    if (RELU) {
        float* sq = br ? sq1 : sq0;
        float ss = 0.f;
#pragma unroll
        for (int j = 0; j < 8; ++j) ss = fmaf(o[j], o[j], ss);
        ss += __shfl_xor(ss, 8);
        ss += __shfl_xor(ss, 4);
        ss += __shfl_xor(ss, 2);
        ss += __shfl_xor(ss, 1);
        if (lane == 0) sq[wid] = ss;
    }
}

// ---------------- semantic attention fusion ----------------
__global__ __launch_bounds__(256) void attn_kernel(const float* __restrict__ x1A,
                                                   const float* __restrict__ x1B,
                                                   const float* __restrict__ x2A,
                                                   const float* __restrict__ x2B,
                                                   const float* __restrict__ A1,
                                                   const float* __restrict__ ab1,
                                                   const float* __restrict__ A2,
                                                   float* __restrict__ out, int n) {
    __shared__ float sA1[DF * HATT];
    __shared__ float sA2[HATT];
    __shared__ float sab[HATT];
    int tid = threadIdx.x;
    for (int i = tid; i < DF * HATT; i += 256) sA1[i] = A1[i];
    if (tid < HATT) { sA2[tid] = A2[tid]; sab[tid] = ab1[tid]; }
    __syncthreads();
    int lane = tid & 63;
    int wib = tid >> 6;
    int wid = blockIdx.x * 4 + wib;
    int nw = gridDim.x * 4;
    for (int i = wid; i < n; i += nw) {
        float u0 = x1A[(size_t)i * 64 + lane], u1 = x1B[(size_t)i * 64 + lane];
        float v0 = x2A[(size_t)i * 64 + lane], v1 = x2B[(size_t)i * 64 + lane];
        float acc1 = 0.f, acc2 = 0.f;
#pragma unroll 4
        for (int d = 0; d < 64; ++d) {
            float w = sA1[d * HATT + lane];
            acc1 = fmaf(__shfl(u0, d), w, acc1);
            acc2 = fmaf(__shfl(v0, d), w, acc2);
        }
#pragma unroll 4
        for (int d = 0; d < 64; ++d) {
            float w = sA1[(d + 64) * HATT + lane];
            acc1 = fmaf(__shfl(u1, d), w, acc1);
            acc2 = fmaf(__shfl(v1, d), w, acc2);
        }
        float t1 = tanhf(acc1 + sab[lane]) * sA2[lane];
        float t2 = tanhf(acc2 + sab[lane]) * sA2[lane];
        for (int off = 32; off; off >>= 1) {
            t1 += __shfl_xor(t1, off);
            t2 += __shfl_xor(t2, off);
        }
        float mx = fmaxf(t1, t2);
        float e1 = expf(t1 - mx), e2 = expf(t2 - mx);
        float inv = 1.f / (e1 + e2);
        float be1 = e1 * inv, be2 = e2 * inv;
        out[(size_t)i * DF + lane] = be1 * u0 + be2 * v0;
        out[(size_t)i * DF + 64 + lane] = be1 * u1 + be2 * v1;
    }
}

// ---------------- launch ----------------

extern "C" void kernel_launch(void* const* d_in, const int* in_sizes, int n_in,
                              void* d_out, int out_size, void* d_ws, size_t ws_size,
                              hipStream_t stream) {
    const float* x  = (const float*)d_in[0];
    const int* row  = (const int*)d_in[1];
    const int* col  = (const int*)d_in[2];
    const float* W1 = (const float*)d_in[3];
    const float* b1 = (const float*)d_in[4];
    const float* W2 = (const float*)d_in[5];
    const float* b2 = (const float*)d_in[6];
    const float* A1 = (const float*)d_in[7];
    const float* ab1= (const float*)d_in[8];
    const float* A2 = (const float*)d_in[9];
    const int N = in_sizes[0] / DF;
    const int E = in_sizes[1];
    float* out = (float*)d_out;

    char* p = (char*)d_ws;
    auto alloc_b = [&](size_t bytes) -> char* {
        char* r = p;
        p += (bytes + 255) & ~(size_t)255;
        return r;
    };
    float* xA    = (float*)alloc_b((size_t)N * 64 * 4);
    float* xB    = (float*)alloc_b((size_t)N * 64 * 4);
    unsigned short* hab  = (unsigned short*)alloc_b((size_t)N * DF * 2);  // bf16 [n][128], also h1ab
    unsigned short* h2ab = (unsigned short*)alloc_b((size_t)N * DF * 2);
    float* x1A   = (float*)alloc_b((size_t)N * 64 * 4);
    float* x1B   = (float*)alloc_b((size_t)N * 64 * 4);
    float* x2A   = (float*)alloc_b((size_t)N * 64 * 4);
    float* x2B   = (float*)alloc_b((size_t)N * 64 * 4);
    float* wsA   = (float*)alloc_b((size_t)E * 4);
    float* wsB   = (float*)alloc_b((size_t)E * 4);
    float* dp0   = (float*)alloc_b((size_t)E * 4);
    float* dp1   = (float*)alloc_b((size_t)E * 4);
    float* disA  = (float*)alloc_b((size_t)N * 4);
    float* disB  = (float*)alloc_b((size_t)N * 4);
    float* sqnx  = (float*)alloc_b((size_t)N * 4);
    float* sqn1  = (float*)alloc_b((size_t)N * 4);
    float* sqn2  = (float*)alloc_b((size_t)N * 4);
    int* cnt2    = (int*)alloc_b((size_t)SL * N * 4);
    int* tot     = (int*)alloc_b((size_t)N * 4);
    int* rowptr  = (int*)alloc_b((size_t)(N + 1) * 4);
    unsigned short* col_s = (unsigned short*)alloc_b((size_t)E * 2);
    (void)ws_size; (void)n_in; (void)out_size;

    const int nodeBlocks  = divup(N * 64, 256);   // 2500
    const int pairBlocks  = 2 * nodeBlocks;       // 5000
    const int mmBlocks    = divup(divup(N, 4), 4);
    const int mm2Blocks   = 2 * mmBlocks;
    const int vecBlocks   = divup(E / 4, 256);
    const int ranges = divup(N, RPB);
    const int rpb    = divup(N, ranges);
    int es = divup(E, SL); es = (es + 3) & ~3;
    const int prepBlocks = ranges * SL;

    // graph prep
    hist2_kernel<<<prepBlocks, 256, 0, stream>>>(row, cnt2, E, N, ranges, rpb, es);
    split_x_kernel<<<nodeBlocks, 256, 0, stream>>>(x, xA, xB, sqnx, N);
    scanRT_kernel<<<divup(N, 64), 256, 0, stream>>>(cnt2, tot, N);
    scanT_kernel<<<1, 1024, 0, stream>>>(tot, rowptr, N);
    scatter2_kernel<<<prepBlocks, 256, 0, stream>>>(row, col, cnt2, rowptr, col_s, E, N, ranges, rpb, es);

    // shared layer-1 transform -> interleaved bf16 h
    mm_kernel<<<mmBlocks, 256, 0, stream>>>(x, x + 64, DF, W1, hab, N);

    // layer-1 edge weights (fp32 chain) + fused degrees
    edgewA_kernel<<<nodeBlocks, 256, 0, stream>>>(xA, col_s, rowptr, dp0, N);
    edgewB1_kernel<<<nodeBlocks, 256, 0, stream>>>(xB, sqnx, col_s, rowptr, dp0,
                                                   wsA, wsB, disA, disB, N);
    scale_wd_kernel<<<vecBlocks, 256, 0, stream>>>(wsA, wsB, col_s, disA, disB, E / 4);

    // layer-1 SpMM: wave per (node, branch); both branches share hab
    spmm_kernel<1><<<pairBlocks, 256, 0, stream>>>(hab, hab, wsA, wsB, col_s, disA, disB,
                                                   rowptr, b1, x1A, x1B, x2A, x2B,
                                                   sqn1, sqn2, N);

    // layer-2 edge weights, both branches paired (fp32 chain)
    edgewA2_kernel<<<pairBlocks, 256, 0, stream>>>(x1A, x2A, col_s, rowptr, dp0, dp1, N);
    edgewB2_kernel<<<pairBlocks, 256, 0, stream>>>(x1B, x2B, sqn1, sqn2,
                                                   col_s, rowptr, dp0, dp1,
                                                   wsA, wsB, disA, disB, N);
    scale_wd_kernel<<<vecBlocks, 256, 0, stream>>>(wsA, wsB, col_s, disA, disB, E / 4);

    // layer-2 transforms, both branches paired -> interleaved bf16 h
    mm2_kernel<<<mm2Blocks, 256, 0, stream>>>(x1A, x1B, x2A, x2B, W2, hab, h2ab, N);

    // layer-2 SpMM: branch parity, full-row gathers
    spmm_kernel<0><<<pairBlocks, 256, 0, stream>>>(hab, h2ab, wsA, wsB, col_s, disA, disB,
                                                   rowptr, b2, x1A, x1B, x2A, x2B,
                                                   sqn1, sqn2, N);

    // semantic attention fusion -> out
    attn_kernel<<<divup(N, 4), 256, 0, stream>>>(x1A, x1B, x2A, x2B, A1, ab1, A2, out, N);
}

// Round 16
// 342.213 us; speedup vs baseline: 1.0260x; 1.0260x over previous
//
#include <hip/hip_runtime.h>
#include <cstdint>
#include <cstddef>

#define DF 128      // feature dim
#define HATT 64     // attention hidden dim
#define SL 64       // edge slices for graph prep
#define RPB 1280    // max rows per range-block (LDS counters)

static inline int divup(int a, int b) { return (a + b - 1) / b; }

typedef int vint4 __attribute__((ext_vector_type(4)));              // nontemporal-compatible
typedef unsigned short vus8 __attribute__((ext_vector_type(8)));    // bf16x8 gather (16B)

struct U16x4 { unsigned short x, y, z, w; };

// bf16 round-to-nearest-even (LINEAR aggregation only; weight->deg->rsqrt chain stays fp32)
static __device__ __forceinline__ unsigned short f2bf(float f) {
    unsigned int u = __float_as_uint(f);
    u = (u + 0x7FFFu + ((u >> 16) & 1u)) >> 16;
    return (unsigned short)u;
}
static __device__ __forceinline__ float bf2f(unsigned short b) {
    return __uint_as_float(((unsigned int)b) << 16);
}

// ---------------- graph prep ----------------
__global__ __launch_bounds__(256) void hist2_kernel(const int* __restrict__ row,
                                                    int* __restrict__ cnt2,
                                                    int E, int n, int ranges, int rpb, int es) {
    int rb = blockIdx.x % ranges;
    int s  = blockIdx.x / ranges;
    int lo = rb * rpb, hi = min(lo + rpb, n);
    int rows = hi - lo;
    __shared__ int lc[RPB];
    for (int j = threadIdx.x; j < rows; j += 256) lc[j] = 0;
    __syncthreads();
    int i0 = s * es, i1 = min(i0 + es, E);
    const vint4* rv = (const vint4*)row;
    for (int j = i0 / 4 + threadIdx.x; j < i1 / 4; j += 256) {
        vint4 r4 = __builtin_nontemporal_load(rv + j);
        if (r4.x >= lo && r4.x < hi) atomicAdd(&lc[r4.x - lo], 1);
        if (r4.y >= lo && r4.y < hi) atomicAdd(&lc[r4.y - lo], 1);
        if (r4.z >= lo && r4.z < hi) atomicAdd(&lc[r4.z - lo], 1);
        if (r4.w >= lo && r4.w < hi) atomicAdd(&lc[r4.w - lo], 1);
    }
    __syncthreads();
    for (int j = threadIdx.x; j < rows; j += 256) cnt2[(size_t)s * n + lo + j] = lc[j];
}

__global__ __launch_bounds__(256) void scanRT_kernel(int* __restrict__ cnt2,
                                                     int* __restrict__ tot, int n) {
    __shared__ int tile[SL][65];
    int r0 = blockIdx.x * 64;
    int w = threadIdx.x >> 6;
    int lane = threadIdx.x & 63;
    int rows = min(64, n - r0);
    for (int s = w; s < SL; s += 4) {
        int v = (lane < rows) ? cnt2[(size_t)s * n + r0 + lane] : 0;
        tile[s][lane] = v;
    }
    __syncthreads();
    int t = threadIdx.x;
    if (t < rows) {
        int run = 0;
#pragma unroll
        for (int s = 0; s < SL; ++s) {
            int v = tile[s][t];
            tile[s][t] = run;
            run += v;
        }
        tot[r0 + t] = run;
    }
    __syncthreads();
    for (int s = w; s < SL; s += 4) {
        if (lane < rows) cnt2[(size_t)s * n + r0 + lane] = tile[s][lane];
    }
}

__global__ __launch_bounds__(1024) void scanT_kernel(const int* __restrict__ tot,
                                                     int* __restrict__ row_ptr, int n) {
    __shared__ int sums[1024];
    int t = threadIdx.x;
    int chunk = (n + 1023) >> 10;
    int start = t * chunk, end = min(start + chunk, n);
    int s = 0;
    for (int r = start; r < end; ++r) s += tot[r];
    sums[t] = s;
    __syncthreads();
    for (int off = 1; off < 1024; off <<= 1) {
        int v = (t >= off) ? sums[t - off] : 0;
        __syncthreads();
        sums[t] += v;
        __syncthreads();
    }
    int run = sums[t] - s;
    for (int r = start; r < end; ++r) {
        row_ptr[r] = run;
        run += tot[r];
    }
    if (t == 1023) row_ptr[n] = sums[1023];
}

__global__ __launch_bounds__(256) void scatter2_kernel(const int* __restrict__ row,
                                                       const int* __restrict__ col,
                                                       const int* __restrict__ cnt2,
                                                       const int* __restrict__ row_ptr,
                                                       unsigned short* __restrict__ col_s,
                                                       int E, int n, int ranges, int rpb, int es) {
    int rb = blockIdx.x % ranges;
    int s  = blockIdx.x / ranges;
    int lo = rb * rpb, hi = min(lo + rpb, n);
    int rows = hi - lo;
    __shared__ int cur[RPB];
    for (int j = threadIdx.x; j < rows; j += 256)
        cur[j] = cnt2[(size_t)s * n + lo + j] + row_ptr[lo + j];
    __syncthreads();
    int i0 = s * es, i1 = min(i0 + es, E);
    const vint4* rv = (const vint4*)row;
    const vint4* cv = (const vint4*)col;
    for (int j = i0 / 4 + threadIdx.x; j < i1 / 4; j += 256) {
        vint4 r4 = __builtin_nontemporal_load(rv + j);
        bool b0 = (r4.x >= lo && r4.x < hi);
        bool b1 = (r4.y >= lo && r4.y < hi);
        bool b2 = (r4.z >= lo && r4.z < hi);
        bool b3 = (r4.w >= lo && r4.w < hi);
        if (b0 | b1 | b2 | b3) {
            vint4 c4 = __builtin_nontemporal_load(cv + j);
            if (b0) { int p = atomicAdd(&cur[r4.x - lo], 1); col_s[p] = (unsigned short)c4.x; }
            if (b1) { int p = atomicAdd(&cur[r4.y - lo], 1); col_s[p] = (unsigned short)c4.y; }
            if (b2) { int p = atomicAdd(&cur[r4.z - lo], 1); col_s[p] = (unsigned short)c4.z; }
            if (b3) { int p = atomicAdd(&cur[r4.w - lo], 1); col_s[p] = (unsigned short)c4.w; }
        }
    }
}

// ---------------- split x + squared norms ----------------
__global__ __launch_bounds__(256) void split_x_kernel(const float* __restrict__ x,
                                                      float* __restrict__ xA,
                                                      float* __restrict__ xB,
                                                      float* __restrict__ sqn, int n) {
    int wid = (blockIdx.x * blockDim.x + threadIdx.x) >> 6;
    int lane = threadIdx.x & 63;
    if (wid >= n) return;
    float v0 = x[(size_t)wid * DF + lane];
    float v1 = x[(size_t)wid * DF + 64 + lane];
    xA[(size_t)wid * 64 + lane] = v0;
    xB[(size_t)wid * 64 + lane] = v1;
    float s = v0 * v0 + v1 * v1;
    for (int off = 32; off; off >>= 1) s += __shfl_xor(s, off);
    if (lane == 0) sqn[wid] = s;
}

// ---------------- edge weights: batched-4 gathers (m==64 path), branchless keep ----------------
// DOT4B: issue 4 independent gathers, then 4 dot/butterfly/selects.
#define DOT4B(TBL, IT4)                                                          \
    {                                                                            \
        int cb = g * 16 + (IT4) * 4;                                             \
        int c0 = __shfl(cc, cb), c1 = __shfl(cc, cb + 1);                        \
        int c2 = __shfl(cc, cb + 2), c3 = __shfl(cc, cb + 3);                    \
        float4 b0 = ((const float4*)(TBL + (size_t)c0 * 64))[sub];               \
        float4 b1 = ((const float4*)(TBL + (size_t)c1 * 64))[sub];               \
        float4 b2 = ((const float4*)(TBL + (size_t)c2 * 64))[sub];               \
        float4 b3 = ((const float4*)(TBL + (size_t)c3 * 64))[sub];               \
        float d0 = a.x * b0.x + a.y * b0.y + a.z * b0.z + a.w * b0.w;            \
        float d1 = a.x * b1.x + a.y * b1.y + a.z * b1.z + a.w * b1.w;            \
        float d2 = a.x * b2.x + a.y * b2.y + a.z * b2.z + a.w * b2.w;            \
        float d3 = a.x * b3.x + a.y * b3.y + a.z * b3.z + a.w * b3.w;            \
        d0 += __shfl_xor(d0, 8); d0 += __shfl_xor(d0, 4);                        \
        d0 += __shfl_xor(d0, 2); d0 += __shfl_xor(d0, 1);                        \
        d1 += __shfl_xor(d1, 8); d1 += __shfl_xor(d1, 4);                        \
        d1 += __shfl_xor(d1, 2); d1 += __shfl_xor(d1, 1);                        \
        d2 += __shfl_xor(d2, 8); d2 += __shfl_xor(d2, 4);                        \
        d2 += __shfl_xor(d2, 2); d2 += __shfl_xor(d2, 1);                        \
        d3 += __shfl_xor(d3, 8); d3 += __shfl_xor(d3, 4);                        \
        d3 += __shfl_xor(d3, 2); d3 += __shfl_xor(d3, 1);                        \
        dkeep = (sub == (IT4) * 4 + 0) ? d0 : dkeep;                             \
        dkeep = (sub == (IT4) * 4 + 1) ? d1 : dkeep;                             \
        dkeep = (sub == (IT4) * 4 + 2) ? d2 : dkeep;                             \
        dkeep = (sub == (IT4) * 4 + 3) ? d3 : dkeep;                             \
    }

// serial tail path (group-uniform guard)
#define DOT_TAIL(TBL)                                                            \
    _Pragma("unroll")                                                            \
    for (int it = 0; it < 16; ++it) {                                            \
        int idx = g * 16 + it;                                                   \
        int c = __shfl(cc, idx);                                                 \
        if (idx < m) {                                                           \
            float4 b = ((const float4*)(TBL + (size_t)c * 64))[sub];             \
            float d = a.x * b.x + a.y * b.y + a.z * b.z + a.w * b.w;             \
            d += __shfl_xor(d, 8); d += __shfl_xor(d, 4);                        \
            d += __shfl_xor(d, 2); d += __shfl_xor(d, 1);                        \
            dkeep = (sub == it) ? d : dkeep;                                     \
        }                                                                        \
    }

__global__ __launch_bounds__(256) void edgewA_kernel(const float* __restrict__ tA,
                                                     const unsigned short* __restrict__ col_s,
                                                     const int* __restrict__ row_ptr,
                                                     float* __restrict__ dpart, int n) {
    int wid = (blockIdx.x * blockDim.x + threadIdx.x) >> 6;
    int lane = threadIdx.x & 63;
    if (wid >= n) return;
    int sub = lane & 15, g = lane >> 4;
    int s = row_ptr[wid], e = row_ptr[wid + 1];
    float4 a = ((const float4*)(tA + (size_t)wid * 64))[sub];
    for (int base = s; base < e; base += 64) {
        int m = e - base; if (m > 64) m = 64;
        int cc = 0;
        if (lane < m) cc = (int)col_s[base + lane];
        float dkeep = 0.f;
        if (m == 64) {
#pragma unroll
            for (int it4 = 0; it4 < 4; ++it4) DOT4B(tA, it4)
        } else {
            DOT_TAIL(tA)
        }
        if (lane < m) dpart[base + lane] = dkeep;
    }
}

__global__ __launch_bounds__(256) void edgewB1_kernel(const float* __restrict__ tB,
                                                      const float* __restrict__ sqn,
                                                      const unsigned short* __restrict__ col_s,
                                                      const int* __restrict__ row_ptr,
                                                      const float* __restrict__ dpart,
                                                      float* __restrict__ wA,
                                                      float* __restrict__ wB,
                                                      float* __restrict__ disA,
                                                      float* __restrict__ disB, int n) {
    int wid = (blockIdx.x * blockDim.x + threadIdx.x) >> 6;
    int lane = threadIdx.x & 63;
    if (wid >= n) return;
    int sub = lane & 15, g = lane >> 4;
    int s = row_ptr[wid], e = row_ptr[wid + 1];
    float4 a = ((const float4*)(tB + (size_t)wid * 64))[sub];
    float na = sqn[wid];
    float accA = 0.f, accB = 0.f;
    for (int base = s; base < e; base += 64) {
        int m = e - base; if (m > 64) m = 64;
        int cc = 0; float dp = 0.f;
        if (lane < m) {
            cc = (int)col_s[base + lane];
            dp = dpart[base + lane];
        }
        float dkeep = 0.f;
        if (m == 64) {
#pragma unroll
            for (int it4 = 0; it4 < 4; ++it4) DOT4B(tB, it4)
        } else {
            DOT_TAIL(tB)
        }
        if (lane < m) {
            float d = dkeep + dp;
            float nb = sqn[cc];
            float cw = d / fmaxf(sqrtf(na * nb), 1e-8f);
            float ew = sqrtf(fmaxf(na + nb - 2.f * d, 0.f) + 1e-12f);
            wA[base + lane] = cw;
            wB[base + lane] = ew;
            accA += cw;
            accB += ew;
        }
    }
#pragma unroll
    for (int off = 32; off; off >>= 1) {
        accA += __shfl_xor(accA, off);
        accB += __shfl_xor(accB, off);
    }
    if (lane == 0) {
        float dA = 1.f + accA;
        disA[wid] = (dA > 0.f) ? rsqrtf(fmaxf(dA, 1e-12f)) : 0.f;
        float dB = 1.f + accB;
        disB[wid] = (dB > 0.f) ? rsqrtf(fmaxf(dB, 1e-12f)) : 0.f;
    }
}

__global__ __launch_bounds__(256) void edgewA2_kernel(const float* __restrict__ t0,
                                                      const float* __restrict__ t1,
                                                      const unsigned short* __restrict__ col_s,
                                                      const int* __restrict__ row_ptr,
                                                      float* __restrict__ dp0,
                                                      float* __restrict__ dp1, int n) {
    int br = blockIdx.x & 1;
    int wid = (blockIdx.x >> 1) * 4 + (threadIdx.x >> 6);
    int lane = threadIdx.x & 63;
    if (wid >= n) return;
    const float* tA = br ? t1 : t0;
    float* dpart = br ? dp1 : dp0;
    int sub = lane & 15, g = lane >> 4;
    int s = row_ptr[wid], e = row_ptr[wid + 1];
    float4 a = ((const float4*)(tA + (size_t)wid * 64))[sub];
    for (int base = s; base < e; base += 64) {
        int m = e - base; if (m > 64) m = 64;
        int cc = 0;
        if (lane < m) cc = (int)col_s[base + lane];
        float dkeep = 0.f;
        if (m == 64) {
#pragma unroll
            for (int it4 = 0; it4 < 4; ++it4) DOT4B(tA, it4)
        } else {
            DOT_TAIL(tA)
        }
        if (lane < m) dpart[base + lane] = dkeep;
    }
}

__global__ __launch_bounds__(256) void edgewB2_kernel(const float* __restrict__ t0B,
                                                      const float* __restrict__ t1B,
                                                      const float* __restrict__ sqn1,
                                                      const float* __restrict__ sqn2,
                                                      const unsigned short* __restrict__ col_s,
                                                      const int* __restrict__ row_ptr,
                                                      const float* __restrict__ dp0,
                                                      const float* __restrict__ dp1,
                                                      float* __restrict__ wsA,
                                                      float* __restrict__ wsB,
                                                      float* __restrict__ disA,
                                                      float* __restrict__ disB, int n) {
    int br = blockIdx.x & 1;
    int wid = (blockIdx.x >> 1) * 4 + (threadIdx.x >> 6);
    int lane = threadIdx.x & 63;
    if (wid >= n) return;
    const float* tB = br ? t1B : t0B;
    const float* sq = br ? sqn2 : sqn1;
    const float* dpart = br ? dp1 : dp0;
    float* wOut = br ? wsB : wsA;
    float* disOut = br ? disB : disA;
    int sub = lane & 15, g = lane >> 4;
    int s = row_ptr[wid], e = row_ptr[wid + 1];
    float4 a = ((const float4*)(tB + (size_t)wid * 64))[sub];
    float na = sq[wid];
    float acc = 0.f;
    for (int base = s; base < e; base += 64) {
        int m = e - base; if (m > 64) m = 64;
        int cc = 0; float dp = 0.f;
        if (lane < m) {
            cc = (int)col_s[base + lane];
            dp = dpart[base + lane];
        }
        float dkeep = 0.f;
        if (m == 64) {
#pragma unroll
            for (int it4 = 0; it4 < 4; ++it4) DOT4B(tB, it4)
        } else {
            DOT_TAIL(tB)
        }
        if (lane < m) {
            float d = dkeep + dp;
            float nb = sq[cc];
            float w;
            if (br == 0) w = d / fmaxf(sqrtf(na * nb), 1e-8f);
            else w = sqrtf(fmaxf(na + nb - 2.f * d, 0.f) + 1e-12f);
            wOut[base + lane] = w;
            acc += w;
        }
    }
#pragma unroll
    for (int off = 32; off; off >>= 1) acc += __shfl_xor(acc, off);
    if (lane == 0) {
        float dg = 1.f + acc;
        disOut[wid] = (dg > 0.f) ? rsqrtf(fmaxf(dg, 1e-12f)) : 0.f;
    }
}

// ---------------- pre-scale edge weights by dis[col] (in place) ----------------
__global__ __launch_bounds__(256) void scale_wd_kernel(float* __restrict__ wsA,
                                                       float* __restrict__ wsB,
                                                       const unsigned short* __restrict__ col_s,
                                                       const float* __restrict__ disA,
                                                       const float* __restrict__ disB, int E4) {
    int j = blockIdx.x * 256 + threadIdx.x;
    if (j >= E4) return;
    U16x4 c4 = ((const U16x4*)col_s)[j];
    float4 wa = ((const float4*)wsA)[j];
    float4 wb = ((const float4*)wsB)[j];
    wa.x *= disA[c4.x]; wa.y *= disA[c4.y]; wa.z *= disA[c4.z]; wa.w *= disA[c4.w];
    wb.x *= disB[c4.x]; wb.y *= disB[c4.y]; wb.z *= disB[c4.z]; wb.w *= disB[c4.w];
    ((float4*)wsA)[j] = wa;
    ((float4*)wsB)[j] = wb;
}

// ---------------- dense matmuls -> interleaved bf16 h [n][128] ----------------
__global__ __launch_bounds__(256) void mm_kernel(const float* __restrict__ inA,
                                                 const float* __restrict__ inB,
                                                 int strideIn,
                                                 const float* __restrict__ W,
                                                 unsigned short* __restrict__ hab, int n) {
    int wid = (blockIdx.x * blockDim.x + threadIdx.x) >> 6;
    int lane = threadIdx.x & 63;
    int i0 = wid * 4;
    if (i0 >= n) return;
    float v0[4], v1[4];
#pragma unroll
    for (int r = 0; r < 4; ++r) {
        int i = i0 + r;
        if (i < n) { v0[r] = inA[(size_t)i * strideIn + lane]; v1[r] = inB[(size_t)i * strideIn + lane]; }
        else { v0[r] = 0.f; v1[r] = 0.f; }
    }
    float acc0[4] = {0.f, 0.f, 0.f, 0.f};
    float acc1[4] = {0.f, 0.f, 0.f, 0.f};
#pragma unroll 4
    for (int k = 0; k < 64; ++k) {
        float w0 = W[k * DF + lane];
        float w1 = W[k * DF + 64 + lane];
#pragma unroll
        for (int r = 0; r < 4; ++r) {
            float a = __shfl(v0[r], k);
            acc0[r] = fmaf(a, w0, acc0[r]);
            acc1[r] = fmaf(a, w1, acc1[r]);
        }
    }
#pragma unroll 4
    for (int k = 0; k < 64; ++k) {
        float w0 = W[(k + 64) * DF + lane];
        float w1 = W[(k + 64) * DF + 64 + lane];
#pragma unroll
        for (int r = 0; r < 4; ++r) {
            float a = __shfl(v1[r], k);
            acc0[r] = fmaf(a, w0, acc0[r]);
            acc1[r] = fmaf(a, w1, acc1[r]);
        }
    }
#pragma unroll
    for (int r = 0; r < 4; ++r) {
        int i = i0 + r;
        if (i < n) {
            hab[(size_t)i * DF + lane] = f2bf(acc0[r]);
            hab[(size_t)i * DF + 64 + lane] = f2bf(acc1[r]);
        }
    }
}

// paired layer-2 mm: branch parity -> interleaved bf16 h
__global__ __launch_bounds__(256) void mm2_kernel(const float* __restrict__ x1A_,
                                                  const float* __restrict__ x1B_,
                                                  const float* __restrict__ x2A_,
                                                  const float* __restrict__ x2B_,
                                                  const float* __restrict__ W,
                                                  unsigned short* __restrict__ h1ab,
                                                  unsigned short* __restrict__ h2ab, int n) {
    int br = blockIdx.x & 1;
    const float* inA = br ? x2A_ : x1A_;
    const float* inB = br ? x2B_ : x1B_;
    unsigned short* hab = br ? h2ab : h1ab;
    int wid = (blockIdx.x >> 1) * 4 + (threadIdx.x >> 6);
    int lane = threadIdx.x & 63;
    int i0 = wid * 4;
    if (i0 >= n) return;
    float v0[4], v1[4];
#pragma unroll
    for (int r = 0; r < 4; ++r) {
        int i = i0 + r;
        if (i < n) { v0[r] = inA[(size_t)i * 64 + lane]; v1[r] = inB[(size_t)i * 64 + lane]; }
        else { v0[r] = 0.f; v1[r] = 0.f; }
    }
    float acc0[4] = {0.f, 0.f, 0.f, 0.f};
    float acc1[4] = {0.f, 0.f, 0.f, 0.f};
#pragma unroll 4
    for (int k = 0; k < 64; ++k) {
        float w0 = W[k * DF + lane];
        float w1 = W[k * DF + 64 + lane];
#pragma unroll
        for (int r = 0; r < 4; ++r) {
            float a = __shfl(v0[r], k);
            acc0[r] = fmaf(a, w0, acc0[r]);
            acc1[r] = fmaf(a, w1, acc1[r]);
        }
    }
#pragma unroll 4
    for (int k = 0; k < 64; ++k) {
        float w0 = W[(k + 64) * DF + lane];
        float w1 = W[(k + 64) * DF + 64 + lane];
#pragma unroll
        for (int r = 0; r < 4; ++r) {
            float a = __shfl(v1[r], k);
            acc0[r] = fmaf(a, w0, acc0[r]);
            acc1[r] = fmaf(a, w1, acc1[r]);
        }
    }
#pragma unroll
    for (int r = 0; r < 4; ++r) {
        int i = i0 + r;
        if (i < n) {
            hab[(size_t)i * DF + lane] = f2bf(acc0[r]);
            hab[(size_t)i * DF + 64 + lane] = f2bf(acc1[r]);
        }
    }
}

// ---------------- unified SpMM: wave per (node, branch), full-row vus8 gathers ----------------
template <int RELU>
__global__ __launch_bounds__(256) void spmm_kernel(const unsigned short* __restrict__ hab0,
                                                   const unsigned short* __restrict__ hab1,
                                                   const float* __restrict__ wd0,
                                                   const float* __restrict__ wd1,
                                                   const unsigned short* __restrict__ col_s,
                                                   const float* __restrict__ dis0,
                                                   const float* __restrict__ dis1,
                                                   const int* __restrict__ row_ptr,
                                                   const float* __restrict__ bias,
                                                   float* __restrict__ o0A, float* __restrict__ o0B,
                                                   float* __restrict__ o1A, float* __restrict__ o1B,
                                                   float* __restrict__ sq0, float* __restrict__ sq1,
                                                   int n) {
    int br = blockIdx.x & 1;
    const unsigned short* hab = br ? hab1 : hab0;
    const float* wd = br ? wd1 : wd0;
    const float* disp = br ? dis1 : dis0;
    float* outA = br ? o1A : o0A;
    float* outB = br ? o1B : o0B;
    int wid = (blockIdx.x >> 1) * 4 + (threadIdx.x >> 6);
    int lane = threadIdx.x & 63;
    if (wid >= n) return;
    int sub = lane & 15, g = lane >> 4;
    int s = row_ptr[wid], e = row_ptr[wid + 1];
    float di = disp[wid];
    float acc[8];
#pragma unroll
    for (int j = 0; j < 8; ++j) acc[j] = 0.f;
    for (int base = s; base < e; base += 64) {
        int m = e - base; if (m > 64) m = 64;
        int cc = 0; float wv = 0.f;
        if (lane < m) {
            cc = (int)col_s[base + lane];
            wv = wd[base + lane];
        }
#define SPM_BODY(CHK)                                                        \
        _Pragma("unroll")                                                    \
        for (int it = 0; it < 16; ++it) {                                    \
            int idx = it * 4 + g;                                            \
            int c = __shfl(cc, idx);                                         \
            float ce = __shfl(wv, idx);                                      \
            if (CHK) {                                                       \
                vus8 gv = ((const vus8*)(hab + (size_t)c * DF))[sub];        \
                _Pragma("unroll")                                            \
                for (int j = 0; j < 8; ++j)                                  \
                    acc[j] = fmaf(ce, bf2f(gv[j]), acc[j]);                  \
            }                                                                \
        }
        if (m == 64) { SPM_BODY(true) } else { SPM_BODY(idx < m) }
#undef SPM_BODY
    }
#pragma unroll
    for (int off = 16; off <= 32; off <<= 1) {
#pragma unroll
        for (int j = 0; j < 8; ++j) acc[j] += __shfl_xor(acc[j], off);
    }
    vus8 hv = ((const vus8*)(hab + (size_t)wid * DF))[sub];
    float4 bbl = ((const float4*)bias)[sub * 2];
    float4 bbh = ((const float4*)bias)[sub * 2 + 1];
    float o[8];
    o[0] = di * (acc[0] + di * bf2f(hv[0])) + bbl.x;
    o[1] = di * (acc[1] + di * bf2f(hv[1])) + bbl.y;
    o[2] = di * (acc[2] + di * bf2f(hv[2])) + bbl.z;
    o[3] = di * (acc[3] + di * bf2f(hv[3])) + bbl.w;
    o[4] = di * (acc[4] + di * bf2f(hv[4])) + bbh.x;
    o[5] = di * (acc[5] + di * bf2f(hv[5])) + bbh.y;
    o[6] = di * (acc[6] + di * bf2f(hv[6])) + bbh.z;
    o[7] = di * (acc[7] + di * bf2f(hv[7])) + bbh.w;
    if (RELU) {
#pragma unroll
        for (int j = 0; j < 8; ++j) o[j] = fmaxf(o[j], 0.f);
    }
    if (g == 0) {
        float4 lo = make_float4(o[0], o[1], o[2], o[3]);
        float4 hi = make_float4(o[4], o[5], o[6], o[7]);
        if (sub < 8) {
            ((float4*)(outA + (size_t)wid * 64))[sub * 2] = lo;
            ((float4*)(outA + (size_t)wid * 64))[sub * 2 + 1] = hi;
        } else {
            int sb = sub - 8;
            ((float4*)(outB + (size_t)wid * 64))[sb * 2] = lo;
            ((float4*)(outB + (size_t)wid * 64))[sb * 2 + 1] = hi;
        }
    }
    if (RELU) {
        float* sq = br ? sq1 : sq0;
        float ss = 0.f;
#pragma unroll
        for (int j = 0; j < 8; ++j) ss = fmaf(o[j], o[j], ss);
        ss += __shfl_xor(ss, 8);
        ss += __shfl_xor(ss, 4);
        ss += __shfl_xor(ss, 2);
        ss += __shfl_xor(ss, 1);
        if (lane == 0) sq[wid] = ss;
    }
}

// ---------------- semantic attention fusion ----------------
__global__ __launch_bounds__(256) void attn_kernel(const float* __restrict__ x1A,
                                                   const float* __restrict__ x1B,
                                                   const float* __restrict__ x2A,
                                                   const float* __restrict__ x2B,
                                                   const float* __restrict__ A1,
                                                   const float* __restrict__ ab1,
                                                   const float* __restrict__ A2,
                                                   float* __restrict__ out, int n) {
    __shared__ float sA1[DF * HATT];
    __shared__ float sA2[HATT];
    __shared__ float sab[HATT];
    int tid = threadIdx.x;
    for (int i = tid; i < DF * HATT; i += 256) sA1[i] = A1[i];
    if (tid < HATT) { sA2[tid] = A2[tid]; sab[tid] = ab1[tid]; }
    __syncthreads();
    int lane = tid & 63;
    int wib = tid >> 6;
    int wid = blockIdx.x * 4 + wib;
    int nw = gridDim.x * 4;
    for (int i = wid; i < n; i += nw) {
        float u0 = x1A[(size_t)i * 64 + lane], u1 = x1B[(size_t)i * 64 + lane];
        float v0 = x2A[(size_t)i * 64 + lane], v1 = x2B[(size_t)i * 64 + lane];
        float acc1 = 0.f, acc2 = 0.f;
#pragma unroll 4
        for (int d = 0; d < 64; ++d) {
            float w = sA1[d * HATT + lane];
            acc1 = fmaf(__shfl(u0, d), w, acc1);
            acc2 = fmaf(__shfl(v0, d), w, acc2);
        }
#pragma unroll 4
        for (int d = 0; d < 64; ++d) {
            float w = sA1[(d + 64) * HATT + lane];
            acc1 = fmaf(__shfl(u1, d), w, acc1);
            acc2 = fmaf(__shfl(v1, d), w, acc2);
        }
        float t1 = tanhf(acc1 + sab[lane]) * sA2[lane];
        float t2 = tanhf(acc2 + sab[lane]) * sA2[lane];
        for (int off = 32; off; off >>= 1) {
            t1 += __shfl_xor(t1, off);
            t2 += __shfl_xor(t2, off);
        }
        float mx = fmaxf(t1, t2);
        float e1 = expf(t1 - mx), e2 = expf(t2 - mx);
        float inv = 1.f / (e1 + e2);
        float be1 = e1 * inv, be2 = e2 * inv;
        out[(size_t)i * DF + lane] = be1 * u0 + be2 * v0;
        out[(size_t)i * DF + 64 + lane] = be1 * u1 + be2 * v1;
    }
}

// ---------------- launch ----------------

extern "C" void kernel_launch(void* const* d_in, const int* in_sizes, int n_in,
                              void* d_out, int out_size, void* d_ws, size_t ws_size,
                              hipStream_t stream) {
    const float* x  = (const float*)d_in[0];
    const int* row  = (const int*)d_in[1];
    const int* col  = (const int*)d_in[2];
    const float* W1 = (const float*)d_in[3];
    const float* b1 = (const float*)d_in[4];
    const float* W2 = (const float*)d_in[5];
    const float* b2 = (const float*)d_in[6];
    const float* A1 = (const float*)d_in[7];
    const float* ab1= (const float*)d_in[8];
    const float* A2 = (const float*)d_in[9];
    const int N = in_sizes[0] / DF;
    const int E = in_sizes[1];
    float* out = (float*)d_out;

    char* p = (char*)d_ws;
    auto alloc_b = [&](size_t bytes) -> char* {
        char* r = p;
        p += (bytes + 255) & ~(size_t)255;
        return r;
    };
    float* xA    = (float*)alloc_b((size_t)N * 64 * 4);
    float* xB    = (float*)alloc_b((size_t)N * 64 * 4);
    unsigned short* hab  = (unsigned short*)alloc_b((size_t)N * DF * 2);  // bf16 [n][128], also h1ab
    unsigned short* h2ab = (unsigned short*)alloc_b((size_t)N * DF * 2);
    float* x1A   = (float*)alloc_b((size_t)N * 64 * 4);
    float* x1B   = (float*)alloc_b((size_t)N * 64 * 4);
    float* x2A   = (float*)alloc_b((size_t)N * 64 * 4);
    float* x2B   = (float*)alloc_b((size_t)N * 64 * 4);
    float* wsA   = (float*)alloc_b((size_t)E * 4);
    float* wsB   = (float*)alloc_b((size_t)E * 4);
    float* dp0   = (float*)alloc_b((size_t)E * 4);
    float* dp1   = (float*)alloc_b((size_t)E * 4);
    float* disA  = (float*)alloc_b((size_t)N * 4);
    float* disB  = (float*)alloc_b((size_t)N * 4);
    float* sqnx  = (float*)alloc_b((size_t)N * 4);
    float* sqn1  = (float*)alloc_b((size_t)N * 4);
    float* sqn2  = (float*)alloc_b((size_t)N * 4);
    int* cnt2    = (int*)alloc_b((size_t)SL * N * 4);
    int* tot     = (int*)alloc_b((size_t)N * 4);
    int* rowptr  = (int*)alloc_b((size_t)(N + 1) * 4);
    unsigned short* col_s = (unsigned short*)alloc_b((size_t)E * 2);
    (void)ws_size; (void)n_in; (void)out_size;

    const int nodeBlocks  = divup(N * 64, 256);   // 2500
    const int pairBlocks  = 2 * nodeBlocks;       // 5000
    const int mmBlocks    = divup(divup(N, 4), 4);
    const int mm2Blocks   = 2 * mmBlocks;
    const int vecBlocks   = divup(E / 4, 256);
    const int ranges = divup(N, RPB);
    const int rpb    = divup(N, ranges);
    int es = divup(E, SL); es = (es + 3) & ~3;
    const int prepBlocks = ranges * SL;

    // graph prep
    hist2_kernel<<<prepBlocks, 256, 0, stream>>>(row, cnt2, E, N, ranges, rpb, es);
    split_x_kernel<<<nodeBlocks, 256, 0, stream>>>(x, xA, xB, sqnx, N);
    scanRT_kernel<<<divup(N, 64), 256, 0, stream>>>(cnt2, tot, N);
    scanT_kernel<<<1, 1024, 0, stream>>>(tot, rowptr, N);
    scatter2_kernel<<<prepBlocks, 256, 0, stream>>>(row, col, cnt2, rowptr, col_s, E, N, ranges, rpb, es);

    // shared layer-1 transform -> interleaved bf16 h
    mm_kernel<<<mmBlocks, 256, 0, stream>>>(x, x + 64, DF, W1, hab, N);

    // layer-1 edge weights (fp32 chain) + fused degrees
    edgewA_kernel<<<nodeBlocks, 256, 0, stream>>>(xA, col_s, rowptr, dp0, N);
    edgewB1_kernel<<<nodeBlocks, 256, 0, stream>>>(xB, sqnx, col_s, rowptr, dp0,
                                                   wsA, wsB, disA, disB, N);
    scale_wd_kernel<<<vecBlocks, 256, 0, stream>>>(wsA, wsB, col_s, disA, disB, E / 4);

    // layer-1 SpMM: wave per (node, branch); both branches share hab
    spmm_kernel<1><<<pairBlocks, 256, 0, stream>>>(hab, hab, wsA, wsB, col_s, disA, disB,
                                                   rowptr, b1, x1A, x1B, x2A, x2B,
                                                   sqn1, sqn2, N);

    // layer-2 edge weights, both branches paired (fp32 chain)
    edgewA2_kernel<<<pairBlocks, 256, 0, stream>>>(x1A, x2A, col_s, rowptr, dp0, dp1, N);
    edgewB2_kernel<<<pairBlocks, 256, 0, stream>>>(x1B, x2B, sqn1, sqn2,
                                                   col_s, rowptr, dp0, dp1,
                                                   wsA, wsB, disA, disB, N);
    scale_wd_kernel<<<vecBlocks, 256, 0, stream>>>(wsA, wsB, col_s, disA, disB, E / 4);

    // layer-2 transforms, both branches paired -> interleaved bf16 h
    mm2_kernel<<<mm2Blocks, 256, 0, stream>>>(x1A, x1B, x2A, x2B, W2, hab, h2ab, N);

    // layer-2 SpMM: branch parity, full-row gathers
    spmm_kernel<0><<<pairBlocks, 256, 0, stream>>>(hab, h2ab, wsA, wsB, col_s, disA, disB,
                                                   rowptr, b2, x1A, x1B, x2A, x2B,
                                                   sqn1, sqn2, N);

    // semantic attention fusion -> out
    attn_kernel<<<divup(N, 4), 256, 0, stream>>>(x1A, x1B, x2A, x2B, A1, ab1, A2, out, N);
}

// Round 17
// 310.840 us; speedup vs baseline: 1.1295x; 1.1009x over previous
//
#include <hip/hip_runtime.h>
#include <cstdint>
#include <cstddef>

#define DF 128      // feature dim
#define HATT 64     // attention hidden dim
#define SL 64       // edge slices for graph prep
#define RPB 1280    // max rows per range-block (LDS counters)

static inline int divup(int a, int b) { return (a + b - 1) / b; }

typedef int vint4 __attribute__((ext_vector_type(4)));              // nontemporal-compatible
typedef unsigned short vus8 __attribute__((ext_vector_type(8)));    // bf16x8 gather (16B)

struct U16x4 { unsigned short x, y, z, w; };

// bf16 round-to-nearest-even (LINEAR aggregation only; weight->deg->rsqrt chain stays fp32)
static __device__ __forceinline__ unsigned short f2bf(float f) {
    unsigned int u = __float_as_uint(f);
    u = (u + 0x7FFFu + ((u >> 16) & 1u)) >> 16;
    return (unsigned short)u;
}
static __device__ __forceinline__ float bf2f(unsigned short b) {
    return __uint_as_float(((unsigned int)b) << 16);
}

// ---------------- graph prep ----------------
__global__ __launch_bounds__(256) void hist2_kernel(const int* __restrict__ row,
                                                    int* __restrict__ cnt2,
                                                    int E, int n, int ranges, int rpb, int es) {
    int rb = blockIdx.x % ranges;
    int s  = blockIdx.x / ranges;
    int lo = rb * rpb, hi = min(lo + rpb, n);
    int rows = hi - lo;
    __shared__ int lc[RPB];
    for (int j = threadIdx.x; j < rows; j += 256) lc[j] = 0;
    __syncthreads();
    int i0 = s * es, i1 = min(i0 + es, E);
    const vint4* rv = (const vint4*)row;
    for (int j = i0 / 4 + threadIdx.x; j < i1 / 4; j += 256) {
        vint4 r4 = __builtin_nontemporal_load(rv + j);
        if (r4.x >= lo && r4.x < hi) atomicAdd(&lc[r4.x - lo], 1);
        if (r4.y >= lo && r4.y < hi) atomicAdd(&lc[r4.y - lo], 1);
        if (r4.z >= lo && r4.z < hi) atomicAdd(&lc[r4.z - lo], 1);
        if (r4.w >= lo && r4.w < hi) atomicAdd(&lc[r4.w - lo], 1);
    }
    __syncthreads();
    for (int j = threadIdx.x; j < rows; j += 256) cnt2[(size_t)s * n + lo + j] = lc[j];
}

__global__ __launch_bounds__(256) void scanRT_kernel(int* __restrict__ cnt2,
                                                     int* __restrict__ tot, int n) {
    __shared__ int tile[SL][65];
    int r0 = blockIdx.x * 64;
    int w = threadIdx.x >> 6;
    int lane = threadIdx.x & 63;
    int rows = min(64, n - r0);
    for (int s = w; s < SL; s += 4) {
        int v = (lane < rows) ? cnt2[(size_t)s * n + r0 + lane] : 0;
        tile[s][lane] = v;
    }
    __syncthreads();
    int t = threadIdx.x;
    if (t < rows) {
        int run = 0;
#pragma unroll
        for (int s = 0; s < SL; ++s) {
            int v = tile[s][t];
            tile[s][t] = run;
            run += v;
        }
        tot[r0 + t] = run;
    }
    __syncthreads();
    for (int s = w; s < SL; s += 4) {
        if (lane < rows) cnt2[(size_t)s * n + r0 + lane] = tile[s][lane];
    }
}

__global__ __launch_bounds__(1024) void scanT_kernel(const int* __restrict__ tot,
                                                     int* __restrict__ row_ptr, int n) {
    __shared__ int sums[1024];
    int t = threadIdx.x;
    int chunk = (n + 1023) >> 10;
    int start = t * chunk, end = min(start + chunk, n);
    int s = 0;
    for (int r = start; r < end; ++r) s += tot[r];
    sums[t] = s;
    __syncthreads();
    for (int off = 1; off < 1024; off <<= 1) {
        int v = (t >= off) ? sums[t - off] : 0;
        __syncthreads();
        sums[t] += v;
        __syncthreads();
    }
    int run = sums[t] - s;
    for (int r = start; r < end; ++r) {
        row_ptr[r] = run;
        run += tot[r];
    }
    if (t == 1023) row_ptr[n] = sums[1023];
}

__global__ __launch_bounds__(256) void scatter2_kernel(const int* __restrict__ row,
                                                       const int* __restrict__ col,
                                                       const int* __restrict__ cnt2,
                                                       const int* __restrict__ row_ptr,
                                                       unsigned short* __restrict__ col_s,
                                                       int E, int n, int ranges, int rpb, int es) {
    int rb = blockIdx.x % ranges;
    int s  = blockIdx.x / ranges;
    int lo = rb * rpb, hi = min(lo + rpb, n);
    int rows = hi - lo;
    __shared__ int cur[RPB];
    for (int j = threadIdx.x; j < rows; j += 256)
        cur[j] = cnt2[(size_t)s * n + lo + j] + row_ptr[lo + j];
    __syncthreads();
    int i0 = s * es, i1 = min(i0 + es, E);
    const vint4* rv = (const vint4*)row;
    const vint4* cv = (const vint4*)col;
    for (int j = i0 / 4 + threadIdx.x; j < i1 / 4; j += 256) {
        vint4 r4 = __builtin_nontemporal_load(rv + j);
        bool b0 = (r4.x >= lo && r4.x < hi);
        bool b1 = (r4.y >= lo && r4.y < hi);
        bool b2 = (r4.z >= lo && r4.z < hi);
        bool b3 = (r4.w >= lo && r4.w < hi);
        if (b0 | b1 | b2 | b3) {
            vint4 c4 = __builtin_nontemporal_load(cv + j);
            if (b0) { int p = atomicAdd(&cur[r4.x - lo], 1); col_s[p] = (unsigned short)c4.x; }
            if (b1) { int p = atomicAdd(&cur[r4.y - lo], 1); col_s[p] = (unsigned short)c4.y; }
            if (b2) { int p = atomicAdd(&cur[r4.z - lo], 1); col_s[p] = (unsigned short)c4.z; }
            if (b3) { int p = atomicAdd(&cur[r4.w - lo], 1); col_s[p] = (unsigned short)c4.w; }
        }
    }
}

// ---------------- split x + squared norms ----------------
__global__ __launch_bounds__(256) void split_x_kernel(const float* __restrict__ x,
                                                      float* __restrict__ xA,
                                                      float* __restrict__ xB,
                                                      float* __restrict__ sqn, int n) {
    int wid = (blockIdx.x * blockDim.x + threadIdx.x) >> 6;
    int lane = threadIdx.x & 63;
    if (wid >= n) return;
    float v0 = x[(size_t)wid * DF + lane];
    float v1 = x[(size_t)wid * DF + 64 + lane];
    xA[(size_t)wid * 64 + lane] = v0;
    xB[(size_t)wid * 64 + lane] = v1;
    float s = v0 * v0 + v1 * v1;
    for (int off = 32; off; off >>= 1) s += __shfl_xor(s, off);
    if (lane == 0) sqn[wid] = s;
}

// ---------------- edge weights: zero-padded chunks, batched-4 gathers, branchless keep ----------------
// Padding lanes (>= m) carry cc=0 -> gather node 0's row (L1-broadcast-hot); results
// discarded via (sub==it) select + lane<m store/accumulate guards. No divergent tail.
#define DOT4B(TBL, IT4)                                                          \
    {                                                                            \
        int cb = g * 16 + (IT4) * 4;                                             \
        int c0 = __shfl(cc, cb), c1 = __shfl(cc, cb + 1);                        \
        int c2 = __shfl(cc, cb + 2), c3 = __shfl(cc, cb + 3);                    \
        float4 b0 = ((const float4*)(TBL + (size_t)c0 * 64))[sub];               \
        float4 b1 = ((const float4*)(TBL + (size_t)c1 * 64))[sub];               \
        float4 b2 = ((const float4*)(TBL + (size_t)c2 * 64))[sub];               \
        float4 b3 = ((const float4*)(TBL + (size_t)c3 * 64))[sub];               \
        float d0 = a.x * b0.x + a.y * b0.y + a.z * b0.z + a.w * b0.w;            \
        float d1 = a.x * b1.x + a.y * b1.y + a.z * b1.z + a.w * b1.w;            \
        float d2 = a.x * b2.x + a.y * b2.y + a.z * b2.z + a.w * b2.w;            \
        float d3 = a.x * b3.x + a.y * b3.y + a.z * b3.z + a.w * b3.w;            \
        d0 += __shfl_xor(d0, 8); d0 += __shfl_xor(d0, 4);                        \
        d0 += __shfl_xor(d0, 2); d0 += __shfl_xor(d0, 1);                        \
        d1 += __shfl_xor(d1, 8); d1 += __shfl_xor(d1, 4);                        \
        d1 += __shfl_xor(d1, 2); d1 += __shfl_xor(d1, 1);                        \
        d2 += __shfl_xor(d2, 8); d2 += __shfl_xor(d2, 4);                        \
        d2 += __shfl_xor(d2, 2); d2 += __shfl_xor(d2, 1);                        \
        d3 += __shfl_xor(d3, 8); d3 += __shfl_xor(d3, 4);                        \
        d3 += __shfl_xor(d3, 2); d3 += __shfl_xor(d3, 1);                        \
        dkeep = (sub == (IT4) * 4 + 0) ? d0 : dkeep;                             \
        dkeep = (sub == (IT4) * 4 + 1) ? d1 : dkeep;                             \
        dkeep = (sub == (IT4) * 4 + 2) ? d2 : dkeep;                             \
        dkeep = (sub == (IT4) * 4 + 3) ? d3 : dkeep;                             \
    }

__global__ __launch_bounds__(256) void edgewA_kernel(const float* __restrict__ tA,
                                                     const unsigned short* __restrict__ col_s,
                                                     const int* __restrict__ row_ptr,
                                                     float* __restrict__ dpart, int n) {
    int wid = (blockIdx.x * blockDim.x + threadIdx.x) >> 6;
    int lane = threadIdx.x & 63;
    if (wid >= n) return;
    int sub = lane & 15, g = lane >> 4;
    int s = row_ptr[wid], e = row_ptr[wid + 1];
    float4 a = ((const float4*)(tA + (size_t)wid * 64))[sub];
    for (int base = s; base < e; base += 64) {
        int m = e - base; if (m > 64) m = 64;
        int cc = 0;
        if (lane < m) cc = (int)col_s[base + lane];
        float dkeep = 0.f;
#pragma unroll
        for (int it4 = 0; it4 < 4; ++it4) DOT4B(tA, it4)
        if (lane < m) dpart[base + lane] = dkeep;
    }
}

__global__ __launch_bounds__(256) void edgewB1_kernel(const float* __restrict__ tB,
                                                      const float* __restrict__ sqn,
                                                      const unsigned short* __restrict__ col_s,
                                                      const int* __restrict__ row_ptr,
                                                      const float* __restrict__ dpart,
                                                      float* __restrict__ wA,
                                                      float* __restrict__ wB,
                                                      float* __restrict__ disA,
                                                      float* __restrict__ disB, int n) {
    int wid = (blockIdx.x * blockDim.x + threadIdx.x) >> 6;
    int lane = threadIdx.x & 63;
    if (wid >= n) return;
    int sub = lane & 15, g = lane >> 4;
    int s = row_ptr[wid], e = row_ptr[wid + 1];
    float4 a = ((const float4*)(tB + (size_t)wid * 64))[sub];
    float na = sqn[wid];
    float accA = 0.f, accB = 0.f;
    for (int base = s; base < e; base += 64) {
        int m = e - base; if (m > 64) m = 64;
        int cc = 0; float dp = 0.f;
        if (lane < m) {
            cc = (int)col_s[base + lane];
            dp = dpart[base + lane];
        }
        float dkeep = 0.f;
#pragma unroll
        for (int it4 = 0; it4 < 4; ++it4) DOT4B(tB, it4)
        if (lane < m) {
            float d = dkeep + dp;
            float nb = sqn[cc];
            float cw = d / fmaxf(sqrtf(na * nb), 1e-8f);
            float ew = sqrtf(fmaxf(na + nb - 2.f * d, 0.f) + 1e-12f);
            wA[base + lane] = cw;
            wB[base + lane] = ew;
            accA += cw;
            accB += ew;
        }
    }
#pragma unroll
    for (int off = 32; off; off >>= 1) {
        accA += __shfl_xor(accA, off);
        accB += __shfl_xor(accB, off);
    }
    if (lane == 0) {
        float dA = 1.f + accA;
        disA[wid] = (dA > 0.f) ? rsqrtf(fmaxf(dA, 1e-12f)) : 0.f;
        float dB = 1.f + accB;
        disB[wid] = (dB > 0.f) ? rsqrtf(fmaxf(dB, 1e-12f)) : 0.f;
    }
}

__global__ __launch_bounds__(256) void edgewA2_kernel(const float* __restrict__ t0,
                                                      const float* __restrict__ t1,
                                                      const unsigned short* __restrict__ col_s,
                                                      const int* __restrict__ row_ptr,
                                                      float* __restrict__ dp0,
                                                      float* __restrict__ dp1, int n) {
    int br = blockIdx.x & 1;
    int wid = (blockIdx.x >> 1) * 4 + (threadIdx.x >> 6);
    int lane = threadIdx.x & 63;
    if (wid >= n) return;
    const float* tA = br ? t1 : t0;
    float* dpart = br ? dp1 : dp0;
    int sub = lane & 15, g = lane >> 4;
    int s = row_ptr[wid], e = row_ptr[wid + 1];
    float4 a = ((const float4*)(tA + (size_t)wid * 64))[sub];
    for (int base = s; base < e; base += 64) {
        int m = e - base; if (m > 64) m = 64;
        int cc = 0;
        if (lane < m) cc = (int)col_s[base + lane];
        float dkeep = 0.f;
#pragma unroll
        for (int it4 = 0; it4 < 4; ++it4) DOT4B(tA, it4)
        if (lane < m) dpart[base + lane] = dkeep;
    }
}

__global__ __launch_bounds__(256) void edgewB2_kernel(const float* __restrict__ t0B,
                                                      const float* __restrict__ t1B,
                                                      const float* __restrict__ sqn1,
                                                      const float* __restrict__ sqn2,
                                                      const unsigned short* __restrict__ col_s,
                                                      const int* __restrict__ row_ptr,
                                                      const float* __restrict__ dp0,
                                                      const float* __restrict__ dp1,
                                                      float* __restrict__ wsA,
                                                      float* __restrict__ wsB,
                                                      float* __restrict__ disA,
                                                      float* __restrict__ disB, int n) {
    int br = blockIdx.x & 1;
    int wid = (blockIdx.x >> 1) * 4 + (threadIdx.x >> 6);
    int lane = threadIdx.x & 63;
    if (wid >= n) return;
    const float* tB = br ? t1B : t0B;
    const float* sq = br ? sqn2 : sqn1;
    const float* dpart = br ? dp1 : dp0;
    float* wOut = br ? wsB : wsA;
    float* disOut = br ? disB : disA;
    int sub = lane & 15, g = lane >> 4;
    int s = row_ptr[wid], e = row_ptr[wid + 1];
    float4 a = ((const float4*)(tB + (size_t)wid * 64))[sub];
    float na = sq[wid];
    float acc = 0.f;
    for (int base = s; base < e; base += 64) {
        int m = e - base; if (m > 64) m = 64;
        int cc = 0; float dp = 0.f;
        if (lane < m) {
            cc = (int)col_s[base + lane];
            dp = dpart[base + lane];
        }
        float dkeep = 0.f;
#pragma unroll
        for (int it4 = 0; it4 < 4; ++it4) DOT4B(tB, it4)
        if (lane < m) {
            float d = dkeep + dp;
            float nb = sq[cc];
            float w;
            if (br == 0) w = d / fmaxf(sqrtf(na * nb), 1e-8f);
            else w = sqrtf(fmaxf(na + nb - 2.f * d, 0.f) + 1e-12f);
            wOut[base + lane] = w;
            acc += w;
        }
    }
#pragma unroll
    for (int off = 32; off; off >>= 1) acc += __shfl_xor(acc, off);
    if (lane == 0) {
        float dg = 1.f + acc;
        disOut[wid] = (dg > 0.f) ? rsqrtf(fmaxf(dg, 1e-12f)) : 0.f;
    }
}

// ---------------- pre-scale edge weights by dis[col] (in place) ----------------
__global__ __launch_bounds__(256) void scale_wd_kernel(float* __restrict__ wsA,
                                                       float* __restrict__ wsB,
                                                       const unsigned short* __restrict__ col_s,
                                                       const float* __restrict__ disA,
                                                       const float* __restrict__ disB, int E4) {
    int j = blockIdx.x * 256 + threadIdx.x;
    if (j >= E4) return;
    U16x4 c4 = ((const U16x4*)col_s)[j];
    float4 wa = ((const float4*)wsA)[j];
    float4 wb = ((const float4*)wsB)[j];
    wa.x *= disA[c4.x]; wa.y *= disA[c4.y]; wa.z *= disA[c4.z]; wa.w *= disA[c4.w];
    wb.x *= disB[c4.x]; wb.y *= disB[c4.y]; wb.z *= disB[c4.z]; wb.w *= disB[c4.w];
    ((float4*)wsA)[j] = wa;
    ((float4*)wsB)[j] = wb;
}

// ---------------- dense matmuls -> interleaved bf16 h [n][128] ----------------
__global__ __launch_bounds__(256) void mm_kernel(const float* __restrict__ inA,
                                                 const float* __restrict__ inB,
                                                 int strideIn,
                                                 const float* __restrict__ W,
                                                 unsigned short* __restrict__ hab, int n) {
    int wid = (blockIdx.x * blockDim.x + threadIdx.x) >> 6;
    int lane = threadIdx.x & 63;
    int i0 = wid * 4;
    if (i0 >= n) return;
    float v0[4], v1[4];
#pragma unroll
    for (int r = 0; r < 4; ++r) {
        int i = i0 + r;
        if (i < n) { v0[r] = inA[(size_t)i * strideIn + lane]; v1[r] = inB[(size_t)i * strideIn + lane]; }
        else { v0[r] = 0.f; v1[r] = 0.f; }
    }
    float acc0[4] = {0.f, 0.f, 0.f, 0.f};
    float acc1[4] = {0.f, 0.f, 0.f, 0.f};
#pragma unroll 4
    for (int k = 0; k < 64; ++k) {
        float w0 = W[k * DF + lane];
        float w1 = W[k * DF + 64 + lane];
#pragma unroll
        for (int r = 0; r < 4; ++r) {
            float a = __shfl(v0[r], k);
            acc0[r] = fmaf(a, w0, acc0[r]);
            acc1[r] = fmaf(a, w1, acc1[r]);
        }
    }
#pragma unroll 4
    for (int k = 0; k < 64; ++k) {
        float w0 = W[(k + 64) * DF + lane];
        float w1 = W[(k + 64) * DF + 64 + lane];
#pragma unroll
        for (int r = 0; r < 4; ++r) {
            float a = __shfl(v1[r], k);
            acc0[r] = fmaf(a, w0, acc0[r]);
            acc1[r] = fmaf(a, w1, acc1[r]);
        }
    }
#pragma unroll
    for (int r = 0; r < 4; ++r) {
        int i = i0 + r;
        if (i < n) {
            hab[(size_t)i * DF + lane] = f2bf(acc0[r]);
            hab[(size_t)i * DF + 64 + lane] = f2bf(acc1[r]);
        }
    }
}

// paired layer-2 mm: branch parity -> interleaved bf16 h
__global__ __launch_bounds__(256) void mm2_kernel(const float* __restrict__ x1A_,
                                                  const float* __restrict__ x1B_,
                                                  const float* __restrict__ x2A_,
                                                  const float* __restrict__ x2B_,
                                                  const float* __restrict__ W,
                                                  unsigned short* __restrict__ h1ab,
                                                  unsigned short* __restrict__ h2ab, int n) {
    int br = blockIdx.x & 1;
    const float* inA = br ? x2A_ : x1A_;
    const float* inB = br ? x2B_ : x1B_;
    unsigned short* hab = br ? h2ab : h1ab;
    int wid = (blockIdx.x >> 1) * 4 + (threadIdx.x >> 6);
    int lane = threadIdx.x & 63;
    int i0 = wid * 4;
    if (i0 >= n) return;
    float v0[4], v1[4];
#pragma unroll
    for (int r = 0; r < 4; ++r) {
        int i = i0 + r;
        if (i < n) { v0[r] = inA[(size_t)i * 64 + lane]; v1[r] = inB[(size_t)i * 64 + lane]; }
        else { v0[r] = 0.f; v1[r] = 0.f; }
    }
    float acc0[4] = {0.f, 0.f, 0.f, 0.f};
    float acc1[4] = {0.f, 0.f, 0.f, 0.f};
#pragma unroll 4
    for (int k = 0; k < 64; ++k) {
        float w0 = W[k * DF + lane];
        float w1 = W[k * DF + 64 + lane];
#pragma unroll
        for (int r = 0; r < 4; ++r) {
            float a = __shfl(v0[r], k);
            acc0[r] = fmaf(a, w0, acc0[r]);
            acc1[r] = fmaf(a, w1, acc1[r]);
        }
    }
#pragma unroll 4
    for (int k = 0; k < 64; ++k) {
        float w0 = W[(k + 64) * DF + lane];
        float w1 = W[(k + 64) * DF + 64 + lane];
#pragma unroll
        for (int r = 0; r < 4; ++r) {
            float a = __shfl(v1[r], k);
            acc0[r] = fmaf(a, w0, acc0[r]);
            acc1[r] = fmaf(a, w1, acc1[r]);
        }
    }
#pragma unroll
    for (int r = 0; r < 4; ++r) {
        int i = i0 + r;
        if (i < n) {
            hab[(size_t)i * DF + lane] = f2bf(acc0[r]);
            hab[(size_t)i * DF + 64 + lane] = f2bf(acc1[r]);
        }
    }
}

// ---------------- unified SpMM: wave per (node, branch), zero-padded, batch-2 gathers ----------------
template <int RELU>
__global__ __launch_bounds__(256) void spmm_kernel(const unsigned short* __restrict__ hab0,
                                                   const unsigned short* __restrict__ hab1,
                                                   const float* __restrict__ wd0,
                                                   const float* __restrict__ wd1,
                                                   const unsigned short* __restrict__ col_s,
                                                   const float* __restrict__ dis0,
                                                   const float* __restrict__ dis1,
                                                   const int* __restrict__ row_ptr,
                                                   const float* __restrict__ bias,
                                                   float* __restrict__ o0A, float* __restrict__ o0B,
                                                   float* __restrict__ o1A, float* __restrict__ o1B,
                                                   float* __restrict__ sq0, float* __restrict__ sq1,
                                                   int n) {
    int br = blockIdx.x & 1;
    const unsigned short* hab = br ? hab1 : hab0;
    const float* wd = br ? wd1 : wd0;
    const float* disp = br ? dis1 : dis0;
    float* outA = br ? o1A : o0A;
    float* outB = br ? o1B : o0B;
    int wid = (blockIdx.x >> 1) * 4 + (threadIdx.x >> 6);
    int lane = threadIdx.x & 63;
    if (wid >= n) return;
    int sub = lane & 15, g = lane >> 4;
    int s = row_ptr[wid], e = row_ptr[wid + 1];
    float di = disp[wid];
    float acc[8];
#pragma unroll
    for (int j = 0; j < 8; ++j) acc[j] = 0.f;
    for (int base = s; base < e; base += 64) {
        int m = e - base; if (m > 64) m = 64;
        int cc = 0; float wv = 0.f;   // padding: cc=0 (L1-hot row 0), wv=0 (fma no-op)
        if (lane < m) {
            cc = (int)col_s[base + lane];
            wv = wd[base + lane];
        }
#pragma unroll
        for (int it2 = 0; it2 < 8; ++it2) {
            int i0 = (it2 * 2 + 0) * 4 + g;
            int i1 = (it2 * 2 + 1) * 4 + g;
            int c0 = __shfl(cc, i0), c1 = __shfl(cc, i1);
            float ce0 = __shfl(wv, i0), ce1 = __shfl(wv, i1);
            vus8 g0 = ((const vus8*)(hab + (size_t)c0 * DF))[sub];
            vus8 g1 = ((const vus8*)(hab + (size_t)c1 * DF))[sub];
#pragma unroll
            for (int j = 0; j < 8; ++j) acc[j] = fmaf(ce0, bf2f(g0[j]), acc[j]);
#pragma unroll
            for (int j = 0; j < 8; ++j) acc[j] = fmaf(ce1, bf2f(g1[j]), acc[j]);
        }
    }
#pragma unroll
    for (int off = 16; off <= 32; off <<= 1) {
#pragma unroll
        for (int j = 0; j < 8; ++j) acc[j] += __shfl_xor(acc[j], off);
    }
    vus8 hv = ((const vus8*)(hab + (size_t)wid * DF))[sub];
    float4 bbl = ((const float4*)bias)[sub * 2];
    float4 bbh = ((const float4*)bias)[sub * 2 + 1];
    float o[8];
    o[0] = di * (acc[0] + di * bf2f(hv[0])) + bbl.x;
    o[1] = di * (acc[1] + di * bf2f(hv[1])) + bbl.y;
    o[2] = di * (acc[2] + di * bf2f(hv[2])) + bbl.z;
    o[3] = di * (acc[3] + di * bf2f(hv[3])) + bbl.w;
    o[4] = di * (acc[4] + di * bf2f(hv[4])) + bbh.x;
    o[5] = di * (acc[5] + di * bf2f(hv[5])) + bbh.y;
    o[6] = di * (acc[6] + di * bf2f(hv[6])) + bbh.z;
    o[7] = di * (acc[7] + di * bf2f(hv[7])) + bbh.w;
    if (RELU) {
#pragma unroll
        for (int j = 0; j < 8; ++j) o[j] = fmaxf(o[j], 0.f);
    }
    if (g == 0) {
        float4 lo = make_float4(o[0], o[1], o[2], o[3]);
        float4 hi = make_float4(o[4], o[5], o[6], o[7]);
        if (sub < 8) {
            ((float4*)(outA + (size_t)wid * 64))[sub * 2] = lo;
            ((float4*)(outA + (size_t)wid * 64))[sub * 2 + 1] = hi;
        } else {
            int sb = sub - 8;
            ((float4*)(outB + (size_t)wid * 64))[sb * 2] = lo;
            ((float4*)(outB + (size_t)wid * 64))[sb * 2 + 1] = hi;
        }
    }
    if (RELU) {
        float* sq = br ? sq1 : sq0;
        float ss = 0.f;
#pragma unroll
        for (int j = 0; j < 8; ++j) ss = fmaf(o[j], o[j], ss);
        ss += __shfl_xor(ss, 8);
        ss += __shfl_xor(ss, 4);
        ss += __shfl_xor(ss, 2);
        ss += __shfl_xor(ss, 1);
        if (lane == 0) sq[wid] = ss;
    }
}

// ---------------- semantic attention fusion ----------------
__global__ __launch_bounds__(256) void attn_kernel(const float* __restrict__ x1A,
                                                   const float* __restrict__ x1B,
                                                   const float* __restrict__ x2A,
                                                   const float* __restrict__ x2B,
                                                   const float* __restrict__ A1,
                                                   const float* __restrict__ ab1,
                                                   const float* __restrict__ A2,
                                                   float* __restrict__ out, int n) {
    __shared__ float sA1[DF * HATT];
    __shared__ float sA2[HATT];
    __shared__ float sab[HATT];
    int tid = threadIdx.x;
    for (int i = tid; i < DF * HATT; i += 256) sA1[i] = A1[i];
    if (tid < HATT) { sA2[tid] = A2[tid]; sab[tid] = ab1[tid]; }
    __syncthreads();
    int lane = tid & 63;
    int wib = tid >> 6;
    int wid = blockIdx.x * 4 + wib;
    int nw = gridDim.x * 4;
    for (int i = wid; i < n; i += nw) {
        float u0 = x1A[(size_t)i * 64 + lane], u1 = x1B[(size_t)i * 64 + lane];
        float v0 = x2A[(size_t)i * 64 + lane], v1 = x2B[(size_t)i * 64 + lane];
        float acc1 = 0.f, acc2 = 0.f;
#pragma unroll 4
        for (int d = 0; d < 64; ++d) {
            float w = sA1[d * HATT + lane];
            acc1 = fmaf(__shfl(u0, d), w, acc1);
            acc2 = fmaf(__shfl(v0, d), w, acc2);
        }
#pragma unroll 4
        for (int d = 0; d < 64; ++d) {
            float w = sA1[(d + 64) * HATT + lane];
            acc1 = fmaf(__shfl(u1, d), w, acc1);
            acc2 = fmaf(__shfl(v1, d), w, acc2);
        }
        float t1 = tanhf(acc1 + sab[lane]) * sA2[lane];
        float t2 = tanhf(acc2 + sab[lane]) * sA2[lane];
        for (int off = 32; off; off >>= 1) {
            t1 += __shfl_xor(t1, off);
            t2 += __shfl_xor(t2, off);
        }
        float mx = fmaxf(t1, t2);
        float e1 = expf(t1 - mx), e2 = expf(t2 - mx);
        float inv = 1.f / (e1 + e2);
        float be1 = e1 * inv, be2 = e2 * inv;
        out[(size_t)i * DF + lane] = be1 * u0 + be2 * v0;
        out[(size_t)i * DF + 64 + lane] = be1 * u1 + be2 * v1;
    }
}

// ---------------- launch ----------------

extern "C" void kernel_launch(void* const* d_in, const int* in_sizes, int n_in,
                              void* d_out, int out_size, void* d_ws, size_t ws_size,
                              hipStream_t stream) {
    const float* x  = (const float*)d_in[0];
    const int* row  = (const int*)d_in[1];
    const int* col  = (const int*)d_in[2];
    const float* W1 = (const float*)d_in[3];
    const float* b1 = (const float*)d_in[4];
    const float* W2 = (const float*)d_in[5];
    const float* b2 = (const float*)d_in[6];
    const float* A1 = (const float*)d_in[7];
    const float* ab1= (const float*)d_in[8];
    const float* A2 = (const float*)d_in[9];
    const int N = in_sizes[0] / DF;
    const int E = in_sizes[1];
    float* out = (float*)d_out;

    char* p = (char*)d_ws;
    auto alloc_b = [&](size_t bytes) -> char* {
        char* r = p;
        p += (bytes + 255) & ~(size_t)255;
        return r;
    };
    float* xA    = (float*)alloc_b((size_t)N * 64 * 4);
    float* xB    = (float*)alloc_b((size_t)N * 64 * 4);
    unsigned short* hab  = (unsigned short*)alloc_b((size_t)N * DF * 2);  // bf16 [n][128], also h1ab
    unsigned short* h2ab = (unsigned short*)alloc_b((size_t)N * DF * 2);
    float* x1A   = (float*)alloc_b((size_t)N * 64 * 4);
    float* x1B   = (float*)alloc_b((size_t)N * 64 * 4);
    float* x2A   = (float*)alloc_b((size_t)N * 64 * 4);
    float* x2B   = (float*)alloc_b((size_t)N * 64 * 4);
    float* wsA   = (float*)alloc_b((size_t)E * 4);
    float* wsB   = (float*)alloc_b((size_t)E * 4);
    float* dp0   = (float*)alloc_b((size_t)E * 4);
    float* dp1   = (float*)alloc_b((size_t)E * 4);
    float* disA  = (float*)alloc_b((size_t)N * 4);
    float* disB  = (float*)alloc_b((size_t)N * 4);
    float* sqnx  = (float*)alloc_b((size_t)N * 4);
    float* sqn1  = (float*)alloc_b((size_t)N * 4);
    float* sqn2  = (float*)alloc_b((size_t)N * 4);
    int* cnt2    = (int*)alloc_b((size_t)SL * N * 4);
    int* tot     = (int*)alloc_b((size_t)N * 4);
    int* rowptr  = (int*)alloc_b((size_t)(N + 1) * 4);
    unsigned short* col_s = (unsigned short*)alloc_b((size_t)E * 2);
    (void)ws_size; (void)n_in; (void)out_size;

    const int nodeBlocks  = divup(N * 64, 256);   // 2500
    const int pairBlocks  = 2 * nodeBlocks;       // 5000
    const int mmBlocks    = divup(divup(N, 4), 4);
    const int mm2Blocks   = 2 * mmBlocks;
    const int vecBlocks   = divup(E / 4, 256);
    const int ranges = divup(N, RPB);
    const int rpb    = divup(N, ranges);
    int es = divup(E, SL); es = (es + 3) & ~3;
    const int prepBlocks = ranges * SL;

    // graph prep
    hist2_kernel<<<prepBlocks, 256, 0, stream>>>(row, cnt2, E, N, ranges, rpb, es);
    split_x_kernel<<<nodeBlocks, 256, 0, stream>>>(x, xA, xB, sqnx, N);
    scanRT_kernel<<<divup(N, 64), 256, 0, stream>>>(cnt2, tot, N);
    scanT_kernel<<<1, 1024, 0, stream>>>(tot, rowptr, N);
    scatter2_kernel<<<prepBlocks, 256, 0, stream>>>(row, col, cnt2, rowptr, col_s, E, N, ranges, rpb, es);

    // shared layer-1 transform -> interleaved bf16 h
    mm_kernel<<<mmBlocks, 256, 0, stream>>>(x, x + 64, DF, W1, hab, N);

    // layer-1 edge weights (fp32 chain) + fused degrees
    edgewA_kernel<<<nodeBlocks, 256, 0, stream>>>(xA, col_s, rowptr, dp0, N);
    edgewB1_kernel<<<nodeBlocks, 256, 0, stream>>>(xB, sqnx, col_s, rowptr, dp0,
                                                   wsA, wsB, disA, disB, N);
    scale_wd_kernel<<<vecBlocks, 256, 0, stream>>>(wsA, wsB, col_s, disA, disB, E / 4);

    // layer-1 SpMM: wave per (node, branch); both branches share hab
    spmm_kernel<1><<<pairBlocks, 256, 0, stream>>>(hab, hab, wsA, wsB, col_s, disA, disB,
                                                   rowptr, b1, x1A, x1B, x2A, x2B,
                                                   sqn1, sqn2, N);

    // layer-2 edge weights, both branches paired (fp32 chain)
    edgewA2_kernel<<<pairBlocks, 256, 0, stream>>>(x1A, x2A, col_s, rowptr, dp0, dp1, N);
    edgewB2_kernel<<<pairBlocks, 256, 0, stream>>>(x1B, x2B, sqn1, sqn2,
                                                   col_s, rowptr, dp0, dp1,
                                                   wsA, wsB, disA, disB, N);
    scale_wd_kernel<<<vecBlocks, 256, 0, stream>>>(wsA, wsB, col_s, disA, disB, E / 4);

    // layer-2 transforms, both branches paired -> interleaved bf16 h
    mm2_kernel<<<mm2Blocks, 256, 0, stream>>>(x1A, x1B, x2A, x2B, W2, hab, h2ab, N);

    // layer-2 SpMM: branch parity, full-row gathers
    spmm_kernel<0><<<pairBlocks, 256, 0, stream>>>(hab, h2ab, wsA, wsB, col_s, disA, disB,
                                                   rowptr, b2, x1A, x1B, x2A, x2B,
                                                   sqn1, sqn2, N);

    // semantic attention fusion -> out
    attn_kernel<<<divup(N, 4), 256, 0, stream>>>(x1A, x1B, x2A, x2B, A1, ab1, A2, out, N);
}

// Round 18
// 310.155 us; speedup vs baseline: 1.1320x; 1.0022x over previous
//
#include <hip/hip_runtime.h>
#include <cstdint>
#include <cstddef>

#define DF 128      // feature dim
#define HATT 64     // attention hidden dim
#define SL 64       // edge slices for graph prep
#define RPB 1280    // max rows per range-block (LDS counters)

static inline int divup(int a, int b) { return (a + b - 1) / b; }

typedef int vint4 __attribute__((ext_vector_type(4)));              // nontemporal-compatible
typedef unsigned short vus8 __attribute__((ext_vector_type(8)));    // bf16x8 gather (16B)

struct U16x4 { unsigned short x, y, z, w; };

// bf16 round-to-nearest-even (LINEAR aggregation only; weight->deg->rsqrt chain stays fp32)
static __device__ __forceinline__ unsigned short f2bf(float f) {
    unsigned int u = __float_as_uint(f);
    u = (u + 0x7FFFu + ((u >> 16) & 1u)) >> 16;
    return (unsigned short)u;
}
static __device__ __forceinline__ float bf2f(unsigned short b) {
    return __uint_as_float(((unsigned int)b) << 16);
}

// ---------------- graph prep ----------------
__global__ __launch_bounds__(256) void hist2_kernel(const int* __restrict__ row,
                                                    int* __restrict__ cnt2,
                                                    int E, int n, int ranges, int rpb, int es) {
    int rb = blockIdx.x % ranges;
    int s  = blockIdx.x / ranges;
    int lo = rb * rpb, hi = min(lo + rpb, n);
    int rows = hi - lo;
    __shared__ int lc[RPB];
    for (int j = threadIdx.x; j < rows; j += 256) lc[j] = 0;
    __syncthreads();
    int i0 = s * es, i1 = min(i0 + es, E);
    const vint4* rv = (const vint4*)row;
    for (int j = i0 / 4 + threadIdx.x; j < i1 / 4; j += 256) {
        vint4 r4 = __builtin_nontemporal_load(rv + j);
        if (r4.x >= lo && r4.x < hi) atomicAdd(&lc[r4.x - lo], 1);
        if (r4.y >= lo && r4.y < hi) atomicAdd(&lc[r4.y - lo], 1);
        if (r4.z >= lo && r4.z < hi) atomicAdd(&lc[r4.z - lo], 1);
        if (r4.w >= lo && r4.w < hi) atomicAdd(&lc[r4.w - lo], 1);
    }
    __syncthreads();
    for (int j = threadIdx.x; j < rows; j += 256) cnt2[(size_t)s * n + lo + j] = lc[j];
}

__global__ __launch_bounds__(256) void scanRT_kernel(int* __restrict__ cnt2,
                                                     int* __restrict__ tot, int n) {
    __shared__ int tile[SL][65];
    int r0 = blockIdx.x * 64;
    int w = threadIdx.x >> 6;
    int lane = threadIdx.x & 63;
    int rows = min(64, n - r0);
    for (int s = w; s < SL; s += 4) {
        int v = (lane < rows) ? cnt2[(size_t)s * n + r0 + lane] : 0;
        tile[s][lane] = v;
    }
    __syncthreads();
    int t = threadIdx.x;
    if (t < rows) {
        int run = 0;
#pragma unroll
        for (int s = 0; s < SL; ++s) {
            int v = tile[s][t];
            tile[s][t] = run;
            run += v;
        }
        tot[r0 + t] = run;
    }
    __syncthreads();
    for (int s = w; s < SL; s += 4) {
        if (lane < rows) cnt2[(size_t)s * n + r0 + lane] = tile[s][lane];
    }
}

__global__ __launch_bounds__(1024) void scanT_kernel(const int* __restrict__ tot,
                                                     int* __restrict__ row_ptr, int n) {
    __shared__ int sums[1024];
    int t = threadIdx.x;
    int chunk = (n + 1023) >> 10;
    int start = t * chunk, end = min(start + chunk, n);
    int s = 0;
    for (int r = start; r < end; ++r) s += tot[r];
    sums[t] = s;
    __syncthreads();
    for (int off = 1; off < 1024; off <<= 1) {
        int v = (t >= off) ? sums[t - off] : 0;
        __syncthreads();
        sums[t] += v;
        __syncthreads();
    }
    int run = sums[t] - s;
    for (int r = start; r < end; ++r) {
        row_ptr[r] = run;
        run += tot[r];
    }
    if (t == 1023) row_ptr[n] = sums[1023];
}

__global__ __launch_bounds__(256) void scatter2_kernel(const int* __restrict__ row,
                                                       const int* __restrict__ col,
                                                       const int* __restrict__ cnt2,
                                                       const int* __restrict__ row_ptr,
                                                       unsigned short* __restrict__ col_s,
                                                       int E, int n, int ranges, int rpb, int es) {
    int rb = blockIdx.x % ranges;
    int s  = blockIdx.x / ranges;
    int lo = rb * rpb, hi = min(lo + rpb, n);
    int rows = hi - lo;
    __shared__ int cur[RPB];
    for (int j = threadIdx.x; j < rows; j += 256)
        cur[j] = cnt2[(size_t)s * n + lo + j] + row_ptr[lo + j];
    __syncthreads();
    int i0 = s * es, i1 = min(i0 + es, E);
    const vint4* rv = (const vint4*)row;
    const vint4* cv = (const vint4*)col;
    for (int j = i0 / 4 + threadIdx.x; j < i1 / 4; j += 256) {
        vint4 r4 = __builtin_nontemporal_load(rv + j);
        bool b0 = (r4.x >= lo && r4.x < hi);
        bool b1 = (r4.y >= lo && r4.y < hi);
        bool b2 = (r4.z >= lo && r4.z < hi);
        bool b3 = (r4.w >= lo && r4.w < hi);
        if (b0 | b1 | b2 | b3) {
            vint4 c4 = __builtin_nontemporal_load(cv + j);
            if (b0) { int p = atomicAdd(&cur[r4.x - lo], 1); col_s[p] = (unsigned short)c4.x; }
            if (b1) { int p = atomicAdd(&cur[r4.y - lo], 1); col_s[p] = (unsigned short)c4.y; }
            if (b2) { int p = atomicAdd(&cur[r4.z - lo], 1); col_s[p] = (unsigned short)c4.z; }
            if (b3) { int p = atomicAdd(&cur[r4.w - lo], 1); col_s[p] = (unsigned short)c4.w; }
        }
    }
}

// ---------------- split x + squared norms ----------------
__global__ __launch_bounds__(256) void split_x_kernel(const float* __restrict__ x,
                                                      float* __restrict__ xA,
                                                      float* __restrict__ xB,
                                                      float* __restrict__ sqn, int n) {
    int wid = (blockIdx.x * blockDim.x + threadIdx.x) >> 6;
    int lane = threadIdx.x & 63;
    if (wid >= n) return;
    float v0 = x[(size_t)wid * DF + lane];
    float v1 = x[(size_t)wid * DF + 64 + lane];
    xA[(size_t)wid * 64 + lane] = v0;
    xB[(size_t)wid * 64 + lane] = v1;
    float s = v0 * v0 + v1 * v1;
    for (int off = 32; off; off >>= 1) s += __shfl_xor(s, off);
    if (lane == 0) sqn[wid] = s;
}

// ---------------- edge weights: zero-padded chunks, batched-4 gathers, branchless keep ----------------
#define DOT4B(TBL, IT4)                                                          \
    {                                                                            \
        int cb = g * 16 + (IT4) * 4;                                             \
        int c0 = __shfl(cc, cb), c1 = __shfl(cc, cb + 1);                        \
        int c2 = __shfl(cc, cb + 2), c3 = __shfl(cc, cb + 3);                    \
        float4 b0 = ((const float4*)(TBL + (size_t)c0 * 64))[sub];               \
        float4 b1 = ((const float4*)(TBL + (size_t)c1 * 64))[sub];               \
        float4 b2 = ((const float4*)(TBL + (size_t)c2 * 64))[sub];               \
        float4 b3 = ((const float4*)(TBL + (size_t)c3 * 64))[sub];               \
        float d0 = a.x * b0.x + a.y * b0.y + a.z * b0.z + a.w * b0.w;            \
        float d1 = a.x * b1.x + a.y * b1.y + a.z * b1.z + a.w * b1.w;            \
        float d2 = a.x * b2.x + a.y * b2.y + a.z * b2.z + a.w * b2.w;            \
        float d3 = a.x * b3.x + a.y * b3.y + a.z * b3.z + a.w * b3.w;            \
        d0 += __shfl_xor(d0, 8); d0 += __shfl_xor(d0, 4);                        \
        d0 += __shfl_xor(d0, 2); d0 += __shfl_xor(d0, 1);                        \
        d1 += __shfl_xor(d1, 8); d1 += __shfl_xor(d1, 4);                        \
        d1 += __shfl_xor(d1, 2); d1 += __shfl_xor(d1, 1);                        \
        d2 += __shfl_xor(d2, 8); d2 += __shfl_xor(d2, 4);                        \
        d2 += __shfl_xor(d2, 2); d2 += __shfl_xor(d2, 1);                        \
        d3 += __shfl_xor(d3, 8); d3 += __shfl_xor(d3, 4);                        \
        d3 += __shfl_xor(d3, 2); d3 += __shfl_xor(d3, 1);                        \
        dkeep = (sub == (IT4) * 4 + 0) ? d0 : dkeep;                             \
        dkeep = (sub == (IT4) * 4 + 1) ? d1 : dkeep;                             \
        dkeep = (sub == (IT4) * 4 + 2) ? d2 : dkeep;                             \
        dkeep = (sub == (IT4) * 4 + 3) ? d3 : dkeep;                             \
    }

__global__ __launch_bounds__(256) void edgewA_kernel(const float* __restrict__ tA,
                                                     const unsigned short* __restrict__ col_s,
                                                     const int* __restrict__ row_ptr,
                                                     float* __restrict__ dpart, int n) {
    int wid = (blockIdx.x * blockDim.x + threadIdx.x) >> 6;
    int lane = threadIdx.x & 63;
    if (wid >= n) return;
    int sub = lane & 15, g = lane >> 4;
    int s = row_ptr[wid], e = row_ptr[wid + 1];
    float4 a = ((const float4*)(tA + (size_t)wid * 64))[sub];
    for (int base = s; base < e; base += 64) {
        int m = e - base; if (m > 64) m = 64;
        int cc = 0;
        if (lane < m) cc = (int)col_s[base + lane];
        float dkeep = 0.f;
#pragma unroll
        for (int it4 = 0; it4 < 4; ++it4) DOT4B(tA, it4)
        if (lane < m) dpart[base + lane] = dkeep;
    }
}

__global__ __launch_bounds__(256) void edgewB1_kernel(const float* __restrict__ tB,
                                                      const float* __restrict__ sqn,
                                                      const unsigned short* __restrict__ col_s,
                                                      const int* __restrict__ row_ptr,
                                                      const float* __restrict__ dpart,
                                                      float* __restrict__ wA,
                                                      float* __restrict__ wB,
                                                      float* __restrict__ disA,
                                                      float* __restrict__ disB, int n) {
    int wid = (blockIdx.x * blockDim.x + threadIdx.x) >> 6;
    int lane = threadIdx.x & 63;
    if (wid >= n) return;
    int sub = lane & 15, g = lane >> 4;
    int s = row_ptr[wid], e = row_ptr[wid + 1];
    float4 a = ((const float4*)(tB + (size_t)wid * 64))[sub];
    float na = sqn[wid];
    float accA = 0.f, accB = 0.f;
    for (int base = s; base < e; base += 64) {
        int m = e - base; if (m > 64) m = 64;
        int cc = 0; float dp = 0.f;
        if (lane < m) {
            cc = (int)col_s[base + lane];
            dp = dpart[base + lane];
        }
        float dkeep = 0.f;
#pragma unroll
        for (int it4 = 0; it4 < 4; ++it4) DOT4B(tB, it4)
        if (lane < m) {
            float d = dkeep + dp;
            float nb = sqn[cc];
            float cw = d / fmaxf(sqrtf(na * nb), 1e-8f);
            float ew = sqrtf(fmaxf(na + nb - 2.f * d, 0.f) + 1e-12f);
            wA[base + lane] = cw;
            wB[base + lane] = ew;
            accA += cw;
            accB += ew;
        }
    }
#pragma unroll
    for (int off = 32; off; off >>= 1) {
        accA += __shfl_xor(accA, off);
        accB += __shfl_xor(accB, off);
    }
    if (lane == 0) {
        float dA = 1.f + accA;
        disA[wid] = (dA > 0.f) ? rsqrtf(fmaxf(dA, 1e-12f)) : 0.f;
        float dB = 1.f + accB;
        disB[wid] = (dB > 0.f) ? rsqrtf(fmaxf(dB, 1e-12f)) : 0.f;
    }
}

__global__ __launch_bounds__(256) void edgewA2_kernel(const float* __restrict__ t0,
                                                      const float* __restrict__ t1,
                                                      const unsigned short* __restrict__ col_s,
                                                      const int* __restrict__ row_ptr,
                                                      float* __restrict__ dp0,
                                                      float* __restrict__ dp1, int n) {
    int br = blockIdx.x & 1;
    int wid = (blockIdx.x >> 1) * 4 + (threadIdx.x >> 6);
    int lane = threadIdx.x & 63;
    if (wid >= n) return;
    const float* tA = br ? t1 : t0;
    float* dpart = br ? dp1 : dp0;
    int sub = lane & 15, g = lane >> 4;
    int s = row_ptr[wid], e = row_ptr[wid + 1];
    float4 a = ((const float4*)(tA + (size_t)wid * 64))[sub];
    for (int base = s; base < e; base += 64) {
        int m = e - base; if (m > 64) m = 64;
        int cc = 0;
        if (lane < m) cc = (int)col_s[base + lane];
        float dkeep = 0.f;
#pragma unroll
        for (int it4 = 0; it4 < 4; ++it4) DOT4B(tA, it4)
        if (lane < m) dpart[base + lane] = dkeep;
    }
}

__global__ __launch_bounds__(256) void edgewB2_kernel(const float* __restrict__ t0B,
                                                      const float* __restrict__ t1B,
                                                      const float* __restrict__ sqn1,
                                                      const float* __restrict__ sqn2,
                                                      const unsigned short* __restrict__ col_s,
                                                      const int* __restrict__ row_ptr,
                                                      const float* __restrict__ dp0,
                                                      const float* __restrict__ dp1,
                                                      float* __restrict__ wsA,
                                                      float* __restrict__ wsB,
                                                      float* __restrict__ disA,
                                                      float* __restrict__ disB, int n) {
    int br = blockIdx.x & 1;
    int wid = (blockIdx.x >> 1) * 4 + (threadIdx.x >> 6);
    int lane = threadIdx.x & 63;
    if (wid >= n) return;
    const float* tB = br ? t1B : t0B;
    const float* sq = br ? sqn2 : sqn1;
    const float* dpart = br ? dp1 : dp0;
    float* wOut = br ? wsB : wsA;
    float* disOut = br ? disB : disA;
    int sub = lane & 15, g = lane >> 4;
    int s = row_ptr[wid], e = row_ptr[wid + 1];
    float4 a = ((const float4*)(tB + (size_t)wid * 64))[sub];
    float na = sq[wid];
    float acc = 0.f;
    for (int base = s; base < e; base += 64) {
        int m = e - base; if (m > 64) m = 64;
        int cc = 0; float dp = 0.f;
        if (lane < m) {
            cc = (int)col_s[base + lane];
            dp = dpart[base + lane];
        }
        float dkeep = 0.f;
#pragma unroll
        for (int it4 = 0; it4 < 4; ++it4) DOT4B(tB, it4)
        if (lane < m) {
            float d = dkeep + dp;
            float nb = sq[cc];
            float w;
            if (br == 0) w = d / fmaxf(sqrtf(na * nb), 1e-8f);
            else w = sqrtf(fmaxf(na + nb - 2.f * d, 0.f) + 1e-12f);
            wOut[base + lane] = w;
            acc += w;
        }
    }
#pragma unroll
    for (int off = 32; off; off >>= 1) acc += __shfl_xor(acc, off);
    if (lane == 0) {
        float dg = 1.f + acc;
        disOut[wid] = (dg > 0.f) ? rsqrtf(fmaxf(dg, 1e-12f)) : 0.f;
    }
}

// ---------------- pre-scale edge weights by dis[col] (in place) ----------------
__global__ __launch_bounds__(256) void scale_wd_kernel(float* __restrict__ wsA,
                                                       float* __restrict__ wsB,
                                                       const unsigned short* __restrict__ col_s,
                                                       const float* __restrict__ disA,
                                                       const float* __restrict__ disB, int E4) {
    int j = blockIdx.x * 256 + threadIdx.x;
    if (j >= E4) return;
    U16x4 c4 = ((const U16x4*)col_s)[j];
    float4 wa = ((const float4*)wsA)[j];
    float4 wb = ((const float4*)wsB)[j];
    wa.x *= disA[c4.x]; wa.y *= disA[c4.y]; wa.z *= disA[c4.z]; wa.w *= disA[c4.w];
    wb.x *= disB[c4.x]; wb.y *= disB[c4.y]; wb.z *= disB[c4.z]; wb.w *= disB[c4.w];
    ((float4*)wsA)[j] = wa;
    ((float4*)wsB)[j] = wb;
}

// ---------------- dense matmuls -> interleaved bf16 h [n][128] ----------------
__global__ __launch_bounds__(256) void mm_kernel(const float* __restrict__ inA,
                                                 const float* __restrict__ inB,
                                                 int strideIn,
                                                 const float* __restrict__ W,
                                                 unsigned short* __restrict__ hab, int n) {
    int wid = (blockIdx.x * blockDim.x + threadIdx.x) >> 6;
    int lane = threadIdx.x & 63;
    int i0 = wid * 4;
    if (i0 >= n) return;
    float v0[4], v1[4];
#pragma unroll
    for (int r = 0; r < 4; ++r) {
        int i = i0 + r;
        if (i < n) { v0[r] = inA[(size_t)i * strideIn + lane]; v1[r] = inB[(size_t)i * strideIn + lane]; }
        else { v0[r] = 0.f; v1[r] = 0.f; }
    }
    float acc0[4] = {0.f, 0.f, 0.f, 0.f};
    float acc1[4] = {0.f, 0.f, 0.f, 0.f};
#pragma unroll 4
    for (int k = 0; k < 64; ++k) {
        float w0 = W[k * DF + lane];
        float w1 = W[k * DF + 64 + lane];
#pragma unroll
        for (int r = 0; r < 4; ++r) {
            float a = __shfl(v0[r], k);
            acc0[r] = fmaf(a, w0, acc0[r]);
            acc1[r] = fmaf(a, w1, acc1[r]);
        }
    }
#pragma unroll 4
    for (int k = 0; k < 64; ++k) {
        float w0 = W[(k + 64) * DF + lane];
        float w1 = W[(k + 64) * DF + 64 + lane];
#pragma unroll
        for (int r = 0; r < 4; ++r) {
            float a = __shfl(v1[r], k);
            acc0[r] = fmaf(a, w0, acc0[r]);
            acc1[r] = fmaf(a, w1, acc1[r]);
        }
    }
#pragma unroll
    for (int r = 0; r < 4; ++r) {
        int i = i0 + r;
        if (i < n) {
            hab[(size_t)i * DF + lane] = f2bf(acc0[r]);
            hab[(size_t)i * DF + 64 + lane] = f2bf(acc1[r]);
        }
    }
}

// paired layer-2 mm: branch parity -> interleaved bf16 h
__global__ __launch_bounds__(256) void mm2_kernel(const float* __restrict__ x1A_,
                                                  const float* __restrict__ x1B_,
                                                  const float* __restrict__ x2A_,
                                                  const float* __restrict__ x2B_,
                                                  const float* __restrict__ W,
                                                  unsigned short* __restrict__ h1ab,
                                                  unsigned short* __restrict__ h2ab, int n) {
    int br = blockIdx.x & 1;
    const float* inA = br ? x2A_ : x1A_;
    const float* inB = br ? x2B_ : x1B_;
    unsigned short* hab = br ? h2ab : h1ab;
    int wid = (blockIdx.x >> 1) * 4 + (threadIdx.x >> 6);
    int lane = threadIdx.x & 63;
    int i0 = wid * 4;
    if (i0 >= n) return;
    float v0[4], v1[4];
#pragma unroll
    for (int r = 0; r < 4; ++r) {
        int i = i0 + r;
        if (i < n) { v0[r] = inA[(size_t)i * 64 + lane]; v1[r] = inB[(size_t)i * 64 + lane]; }
        else { v0[r] = 0.f; v1[r] = 0.f; }
    }
    float acc0[4] = {0.f, 0.f, 0.f, 0.f};
    float acc1[4] = {0.f, 0.f, 0.f, 0.f};
#pragma unroll 4
    for (int k = 0; k < 64; ++k) {
        float w0 = W[k * DF + lane];
        float w1 = W[k * DF + 64 + lane];
#pragma unroll
        for (int r = 0; r < 4; ++r) {
            float a = __shfl(v0[r], k);
            acc0[r] = fmaf(a, w0, acc0[r]);
            acc1[r] = fmaf(a, w1, acc1[r]);
        }
    }
#pragma unroll 4
    for (int k = 0; k < 64; ++k) {
        float w0 = W[(k + 64) * DF + lane];
        float w1 = W[(k + 64) * DF + 64 + lane];
#pragma unroll
        for (int r = 0; r < 4; ++r) {
            float a = __shfl(v1[r], k);
            acc0[r] = fmaf(a, w0, acc0[r]);
            acc1[r] = fmaf(a, w1, acc1[r]);
        }
    }
#pragma unroll
    for (int r = 0; r < 4; ++r) {
        int i = i0 + r;
        if (i < n) {
            hab[(size_t)i * DF + lane] = f2bf(acc0[r]);
            hab[(size_t)i * DF + 64 + lane] = f2bf(acc1[r]);
        }
    }
}

// ---------------- unified SpMM: wave per (node, branch), zero-padded, pipelined batch-4 ----------------
template <int RELU>
__global__ __launch_bounds__(256) void spmm_kernel(const unsigned short* __restrict__ hab0,
                                                   const unsigned short* __restrict__ hab1,
                                                   const float* __restrict__ wd0,
                                                   const float* __restrict__ wd1,
                                                   const unsigned short* __restrict__ col_s,
                                                   const float* __restrict__ dis0,
                                                   const float* __restrict__ dis1,
                                                   const int* __restrict__ row_ptr,
                                                   const float* __restrict__ bias,
                                                   float* __restrict__ o0A, float* __restrict__ o0B,
                                                   float* __restrict__ o1A, float* __restrict__ o1B,
                                                   float* __restrict__ sq0, float* __restrict__ sq1,
                                                   int n) {
    int br = blockIdx.x & 1;
    const unsigned short* hab = br ? hab1 : hab0;
    const float* wd = br ? wd1 : wd0;
    const float* disp = br ? dis1 : dis0;
    float* outA = br ? o1A : o0A;
    float* outB = br ? o1B : o0B;
    int wid = (blockIdx.x >> 1) * 4 + (threadIdx.x >> 6);
    int lane = threadIdx.x & 63;
    if (wid >= n) return;
    int sub = lane & 15, g = lane >> 4;
    int s = row_ptr[wid], e = row_ptr[wid + 1];
    float di = disp[wid];
    float acc[8];
#pragma unroll
    for (int j = 0; j < 8; ++j) acc[j] = 0.f;
    for (int base = s; base < e; base += 64) {
        int m = e - base; if (m > 64) m = 64;
        int cc = 0; float wv = 0.f;   // padding: cc=0 (L1-hot row 0), wv=0 (fma no-op)
        if (lane < m) {
            cc = (int)col_s[base + lane];
            wv = wd[base + lane];
        }
        // software pipeline: 4 gathers in flight (2 live pairs rotating)
        int pc0 = __shfl(cc, 0 * 4 + g), pc1 = __shfl(cc, 1 * 4 + g);
        float pe0 = __shfl(wv, 0 * 4 + g), pe1 = __shfl(wv, 1 * 4 + g);
        vus8 pg0 = ((const vus8*)(hab + (size_t)pc0 * DF))[sub];
        vus8 pg1 = ((const vus8*)(hab + (size_t)pc1 * DF))[sub];
#pragma unroll
        for (int it2 = 0; it2 < 7; ++it2) {
            int i2 = (it2 * 2 + 2) * 4 + g;
            int i3 = (it2 * 2 + 3) * 4 + g;
            int nc0 = __shfl(cc, i2), nc1 = __shfl(cc, i3);
            float ne0 = __shfl(wv, i2), ne1 = __shfl(wv, i3);
            vus8 ng0 = ((const vus8*)(hab + (size_t)nc0 * DF))[sub];
            vus8 ng1 = ((const vus8*)(hab + (size_t)nc1 * DF))[sub];
#pragma unroll
            for (int j = 0; j < 8; ++j) acc[j] = fmaf(pe0, bf2f(pg0[j]), acc[j]);
#pragma unroll
            for (int j = 0; j < 8; ++j) acc[j] = fmaf(pe1, bf2f(pg1[j]), acc[j]);
            pg0 = ng0; pg1 = ng1; pe0 = ne0; pe1 = ne1;
        }
#pragma unroll
        for (int j = 0; j < 8; ++j) acc[j] = fmaf(pe0, bf2f(pg0[j]), acc[j]);
#pragma unroll
        for (int j = 0; j < 8; ++j) acc[j] = fmaf(pe1, bf2f(pg1[j]), acc[j]);
    }
#pragma unroll
    for (int off = 16; off <= 32; off <<= 1) {
#pragma unroll
        for (int j = 0; j < 8; ++j) acc[j] += __shfl_xor(acc[j], off);
    }
    vus8 hv = ((const vus8*)(hab + (size_t)wid * DF))[sub];
    float4 bbl = ((const float4*)bias)[sub * 2];
    float4 bbh = ((const float4*)bias)[sub * 2 + 1];
    float o[8];
    o[0] = di * (acc[0] + di * bf2f(hv[0])) + bbl.x;
    o[1] = di * (acc[1] + di * bf2f(hv[1])) + bbl.y;
    o[2] = di * (acc[2] + di * bf2f(hv[2])) + bbl.z;
    o[3] = di * (acc[3] + di * bf2f(hv[3])) + bbl.w;
    o[4] = di * (acc[4] + di * bf2f(hv[4])) + bbh.x;
    o[5] = di * (acc[5] + di * bf2f(hv[5])) + bbh.y;
    o[6] = di * (acc[6] + di * bf2f(hv[6])) + bbh.z;
    o[7] = di * (acc[7] + di * bf2f(hv[7])) + bbh.w;
    if (RELU) {
#pragma unroll
        for (int j = 0; j < 8; ++j) o[j] = fmaxf(o[j], 0.f);
    }
    if (g == 0) {
        float4 lo = make_float4(o[0], o[1], o[2], o[3]);
        float4 hi = make_float4(o[4], o[5], o[6], o[7]);
        if (sub < 8) {
            ((float4*)(outA + (size_t)wid * 64))[sub * 2] = lo;
            ((float4*)(outA + (size_t)wid * 64))[sub * 2 + 1] = hi;
        } else {
            int sb = sub - 8;
            ((float4*)(outB + (size_t)wid * 64))[sb * 2] = lo;
            ((float4*)(outB + (size_t)wid * 64))[sb * 2 + 1] = hi;
        }
    }
    if (RELU) {
        float* sq = br ? sq1 : sq0;
        float ss = 0.f;
#pragma unroll
        for (int j = 0; j < 8; ++j) ss = fmaf(o[j], o[j], ss);
        ss += __shfl_xor(ss, 8);
        ss += __shfl_xor(ss, 4);
        ss += __shfl_xor(ss, 2);
        ss += __shfl_xor(ss, 1);
        if (lane == 0) sq[wid] = ss;
    }
}

// ---------------- semantic attention fusion ----------------
__global__ __launch_bounds__(256) void attn_kernel(const float* __restrict__ x1A,
                                                   const float* __restrict__ x1B,
                                                   const float* __restrict__ x2A,
                                                   const float* __restrict__ x2B,
                                                   const float* __restrict__ A1,
                                                   const float* __restrict__ ab1,
                                                   const float* __restrict__ A2,
                                                   float* __restrict__ out, int n) {
    __shared__ float sA1[DF * HATT];
    __shared__ float sA2[HATT];
    __shared__ float sab[HATT];
    int tid = threadIdx.x;
    for (int i = tid; i < DF * HATT; i += 256) sA1[i] = A1[i];
    if (tid < HATT) { sA2[tid] = A2[tid]; sab[tid] = ab1[tid]; }
    __syncthreads();
    int lane = tid & 63;
    int wib = tid >> 6;
    int wid = blockIdx.x * 4 + wib;
    int nw = gridDim.x * 4;
    for (int i = wid; i < n; i += nw) {
        float u0 = x1A[(size_t)i * 64 + lane], u1 = x1B[(size_t)i * 64 + lane];
        float v0 = x2A[(size_t)i * 64 + lane], v1 = x2B[(size_t)i * 64 + lane];
        float acc1 = 0.f, acc2 = 0.f;
#pragma unroll 4
        for (int d = 0; d < 64; ++d) {
            float w = sA1[d * HATT + lane];
            acc1 = fmaf(__shfl(u0, d), w, acc1);
            acc2 = fmaf(__shfl(v0, d), w, acc2);
        }
#pragma unroll 4
        for (int d = 0; d < 64; ++d) {
            float w = sA1[(d + 64) * HATT + lane];
            acc1 = fmaf(__shfl(u1, d), w, acc1);
            acc2 = fmaf(__shfl(v1, d), w, acc2);
        }
        float t1 = tanhf(acc1 + sab[lane]) * sA2[lane];
        float t2 = tanhf(acc2 + sab[lane]) * sA2[lane];
        for (int off = 32; off; off >>= 1) {
            t1 += __shfl_xor(t1, off);
            t2 += __shfl_xor(t2, off);
        }
        float mx = fmaxf(t1, t2);
        float e1 = expf(t1 - mx), e2 = expf(t2 - mx);
        float inv = 1.f / (e1 + e2);
        float be1 = e1 * inv, be2 = e2 * inv;
        out[(size_t)i * DF + lane] = be1 * u0 + be2 * v0;
        out[(size_t)i * DF + 64 + lane] = be1 * u1 + be2 * v1;
    }
}

// ---------------- launch ----------------

extern "C" void kernel_launch(void* const* d_in, const int* in_sizes, int n_in,
                              void* d_out, int out_size, void* d_ws, size_t ws_size,
                              hipStream_t stream) {
    const float* x  = (const float*)d_in[0];
    const int* row  = (const int*)d_in[1];
    const int* col  = (const int*)d_in[2];
    const float* W1 = (const float*)d_in[3];
    const float* b1 = (const float*)d_in[4];
    const float* W2 = (const float*)d_in[5];
    const float* b2 = (const float*)d_in[6];
    const float* A1 = (const float*)d_in[7];
    const float* ab1= (const float*)d_in[8];
    const float* A2 = (const float*)d_in[9];
    const int N = in_sizes[0] / DF;
    const int E = in_sizes[1];
    float* out = (float*)d_out;

    char* p = (char*)d_ws;
    auto alloc_b = [&](size_t bytes) -> char* {
        char* r = p;
        p += (bytes + 255) & ~(size_t)255;
        return r;
    };
    float* xA    = (float*)alloc_b((size_t)N * 64 * 4);
    float* xB    = (float*)alloc_b((size_t)N * 64 * 4);
    unsigned short* hab  = (unsigned short*)alloc_b((size_t)N * DF * 2);  // bf16 [n][128], also h1ab
    unsigned short* h2ab = (unsigned short*)alloc_b((size_t)N * DF * 2);
    float* x1A   = (float*)alloc_b((size_t)N * 64 * 4);
    float* x1B   = (float*)alloc_b((size_t)N * 64 * 4);
    float* x2A   = (float*)alloc_b((size_t)N * 64 * 4);
    float* x2B   = (float*)alloc_b((size_t)N * 64 * 4);
    float* wsA   = (float*)alloc_b((size_t)E * 4);
    float* wsB   = (float*)alloc_b((size_t)E * 4);
    float* dp0   = (float*)alloc_b((size_t)E * 4);
    float* dp1   = (float*)alloc_b((size_t)E * 4);
    float* disA  = (float*)alloc_b((size_t)N * 4);
    float* disB  = (float*)alloc_b((size_t)N * 4);
    float* sqnx  = (float*)alloc_b((size_t)N * 4);
    float* sqn1  = (float*)alloc_b((size_t)N * 4);
    float* sqn2  = (float*)alloc_b((size_t)N * 4);
    int* cnt2    = (int*)alloc_b((size_t)SL * N * 4);
    int* tot     = (int*)alloc_b((size_t)N * 4);
    int* rowptr  = (int*)alloc_b((size_t)(N + 1) * 4);
    unsigned short* col_s = (unsigned short*)alloc_b((size_t)E * 2);
    (void)ws_size; (void)n_in; (void)out_size;

    const int nodeBlocks  = divup(N * 64, 256);   // 2500
    const int pairBlocks  = 2 * nodeBlocks;       // 5000
    const int mmBlocks    = divup(divup(N, 4), 4);
    const int mm2Blocks   = 2 * mmBlocks;
    const int vecBlocks   = divup(E / 4, 256);
    const int ranges = divup(N, RPB);
    const int rpb    = divup(N, ranges);
    int es = divup(E, SL); es = (es + 3) & ~3;
    const int prepBlocks = ranges * SL;

    // graph prep
    hist2_kernel<<<prepBlocks, 256, 0, stream>>>(row, cnt2, E, N, ranges, rpb, es);
    split_x_kernel<<<nodeBlocks, 256, 0, stream>>>(x, xA, xB, sqnx, N);
    scanRT_kernel<<<divup(N, 64), 256, 0, stream>>>(cnt2, tot, N);
    scanT_kernel<<<1, 1024, 0, stream>>>(tot, rowptr, N);
    scatter2_kernel<<<prepBlocks, 256, 0, stream>>>(row, col, cnt2, rowptr, col_s, E, N, ranges, rpb, es);

    // shared layer-1 transform -> interleaved bf16 h
    mm_kernel<<<mmBlocks, 256, 0, stream>>>(x, x + 64, DF, W1, hab, N);

    // layer-1 edge weights (fp32 chain) + fused degrees
    edgewA_kernel<<<nodeBlocks, 256, 0, stream>>>(xA, col_s, rowptr, dp0, N);
    edgewB1_kernel<<<nodeBlocks, 256, 0, stream>>>(xB, sqnx, col_s, rowptr, dp0,
                                                   wsA, wsB, disA, disB, N);
    scale_wd_kernel<<<vecBlocks, 256, 0, stream>>>(wsA, wsB, col_s, disA, disB, E / 4);

    // layer-1 SpMM: wave per (node, branch); both branches share hab
    spmm_kernel<1><<<pairBlocks, 256, 0, stream>>>(hab, hab, wsA, wsB, col_s, disA, disB,
                                                   rowptr, b1, x1A, x1B, x2A, x2B,
                                                   sqn1, sqn2, N);

    // layer-2 edge weights, both branches paired (fp32 chain)
    edgewA2_kernel<<<pairBlocks, 256, 0, stream>>>(x1A, x2A, col_s, rowptr, dp0, dp1, N);
    edgewB2_kernel<<<pairBlocks, 256, 0, stream>>>(x1B, x2B, sqn1, sqn2,
                                                   col_s, rowptr, dp0, dp1,
                                                   wsA, wsB, disA, disB, N);
    scale_wd_kernel<<<vecBlocks, 256, 0, stream>>>(wsA, wsB, col_s, disA, disB, E / 4);

    // layer-2 transforms, both branches paired -> interleaved bf16 h
    mm2_kernel<<<mm2Blocks, 256, 0, stream>>>(x1A, x1B, x2A, x2B, W2, hab, h2ab, N);

    // layer-2 SpMM: branch parity, full-row gathers
    spmm_kernel<0><<<pairBlocks, 256, 0, stream>>>(hab, h2ab, wsA, wsB, col_s, disA, disB,
                                                   rowptr, b2, x1A, x1B, x2A, x2B,
                                                   sqn1, sqn2, N);

    // semantic attention fusion -> out
    attn_kernel<<<divup(N, 4), 256, 0, stream>>>(x1A, x1B, x2A, x2B, A1, ab1, A2, out, N);
}